// Round 12
// baseline (303.667 us; speedup 1.0000x reference)
//
#include <hip/hip_runtime.h>
#include <math.h>

#define Bn 32
#define Ln 512
#define Dn 512
#define Hn 8
#define DHn 64
#define FFn 2048
#define Mn (Bn*Ln)   // 16384
#define QKVS 1536

typedef __attribute__((ext_vector_type(4))) float f32x4;
typedef __attribute__((ext_vector_type(8))) short short8;

__device__ __forceinline__ float bf2f(ushort u){ return __uint_as_float(((unsigned)u) << 16); }
__device__ __forceinline__ ushort f2bf(float f){
  unsigned u = __float_as_uint(f);
  u += 0x7FFFu + ((u >> 16) & 1u);
  return (ushort)(u >> 16);
}
// exact sigmoid-form of tanh-gelu: 0.5x(1+tanh(y)) == x*sigmoid(2y)
__device__ __forceinline__ float gelu_fast(float x){
  float y2 = 1.5957691216057308f * (x + 0.044715f*x*x*x);
  return x / (1.0f + __expf(-y2));
}

// async global->LDS, 16B per lane; LDS dest is wave-uniform base + lane*16
__device__ __forceinline__ void gload_lds16(const ushort* g, ushort* l){
  __builtin_amdgcn_global_load_lds(
      (__attribute__((address_space(1))) void*)(void*)g,
      (__attribute__((address_space(3))) void*)(void*)l, 16, 0, 0);
}

__device__ __forceinline__ void cvt4(const float* __restrict__ in, ushort* __restrict__ out, int u){
  float4 v = *(const float4*)(in + u*4);
  ushort4 o;
  o.x = f2bf(v.x); o.y = f2bf(v.y); o.z = f2bf(v.z); o.w = f2bf(v.w);
  *(ushort4*)(out + u*4) = o;
}

// ---------------- fused prep: x cvt + 7 weight cvts + PE table + qkv bias pack ----------------
__global__ __launch_bounds__(256) void prep_kernel(
    const float* __restrict__ x, ushort* __restrict__ xbf,
    const float* __restrict__ Wg, const float* __restrict__ Wq, const float* __restrict__ Wk,
    const float* __restrict__ Wv, const float* __restrict__ Wo, const float* __restrict__ W1,
    const float* __restrict__ W2,
    const float* __restrict__ bq, const float* __restrict__ bk, const float* __restrict__ bv,
    ushort* __restrict__ wgb, ushort* __restrict__ wqkvb, ushort* __restrict__ wob,
    ushort* __restrict__ w1b, ushort* __restrict__ w2b,
    float* __restrict__ pe, float* __restrict__ bqkv)
{
  int u = blockIdx.x*256 + threadIdx.x;
  const int XU = 2097152, WU = 65536, FU = 262144;
  if (u < XU){ cvt4(x, xbf, u); return; }             u -= XU;
  if (u < WU){ cvt4(Wg, wgb, u); return; }            u -= WU;
  if (u < WU){ cvt4(Wq, wqkvb, u); return; }          u -= WU;
  if (u < WU){ cvt4(Wk, wqkvb + 262144, u); return; } u -= WU;
  if (u < WU){ cvt4(Wv, wqkvb + 524288, u); return; } u -= WU;
  if (u < WU){ cvt4(Wo, wob, u); return; }            u -= WU;
  if (u < FU){ cvt4(W1, w1b, u); return; }            u -= FU;
  if (u < FU){ cvt4(W2, w2b, u); return; }            u -= FU;
  if (u < WU){                                        // PE table
    int e = u*4; int l = e >> 9; int d0 = e & 511;
    #pragma unroll
    for (int p=0;p<2;p++){
      int i = (d0 >> 1) + p;
      float dv = expf((float)(2*i) * (-9.210340371976184f/512.0f));
      float ang = (float)l * dv;
      pe[e + 2*p]     = sinf(ang);
      pe[e + 2*p + 1] = cosf(ang);
    }
    return;
  }
  u -= WU;
  if (u < 384){
    int e = u*4;
    #pragma unroll
    for (int j=0;j<4;j++){
      int i = e + j;
      bqkv[i] = (i < 512) ? bq[i] : (i < 1024) ? bk[i-512] : bv[i-1024];
    }
  }
}

// ---------------- GEMM A (R9): BM=256, BN=128, BK=64, 3-ring, 1 barrier/K-tile ----------------
// MODE: 0 gate  2 c+bias+bf16res->f32  3 gelu->bf16  4 gelu+f32res->f32
template<int MODE>
__global__ __launch_bounds__(512) void gemm_kernel(
    const ushort* __restrict__ A, const ushort* __restrict__ W,
    const float* __restrict__ bias,
    const float* __restrict__ res,
    const ushort* __restrict__ rbf,
    const float* __restrict__ spk, const float* __restrict__ pe,
    float* __restrict__ outf, ushort* __restrict__ outb, ushort* __restrict__ outb2,
    int K, int N, int gx)
{
  __shared__ ushort lbuf[3][24576];   // per buf: A 256x64 (16384) | B 128x64 (8192)
  int t = threadIdx.x;
  int wave = t >> 6, lane = t & 63;
  int wrow = wave >> 2, wcol = wave & 3;
  int g = lane >> 4, r16 = lane & 15;

  int nwg = gx * (Mn/256);
  int wg = blockIdx.x;
  int tile = (wg & 7)*(nwg >> 3) + (wg >> 3);
  int trow = tile / gx;
  int tcol = tile - trow*gx;
  int rowBase = trow * 256;
  int colBase = tcol * 128;

  int srow8 = lane >> 3;
  int sucol = ((lane & 7) ^ srow8) * 8;
  const ushort* gA = A + (size_t)(rowBase + wave*8 + srow8)*K + sucol;
  const ushort* gW = W + (size_t)(colBase + wave*8 + srow8)*K + sucol;

  int NT = K >> 6;

  f32x4 acc[8][2];
  #pragma unroll
  for (int m=0;m<8;m++)
    #pragma unroll
    for (int n=0;n<2;n++) acc[m][n] = (f32x4)0.0f;

  #pragma unroll
  for (int c=0;c<4;c++) gload_lds16(gA + (size_t)c*64*K,      &lbuf[0][c*4096 + wave*512]);
  #pragma unroll
  for (int c=0;c<2;c++) gload_lds16(gW + (size_t)c*64*K,      &lbuf[0][16384 + c*4096 + wave*512]);
  #pragma unroll
  for (int c=0;c<4;c++) gload_lds16(gA + (size_t)c*64*K + 64, &lbuf[1][c*4096 + wave*512]);
  #pragma unroll
  for (int c=0;c<2;c++) gload_lds16(gW + (size_t)c*64*K + 64, &lbuf[1][16384 + c*4096 + wave*512]);
  asm volatile("s_waitcnt vmcnt(6)" ::: "memory");
  __builtin_amdgcn_s_barrier();

  int cur = 0, stg = 2;
  for (int kt = 0; kt < NT; ++kt){
    if (kt + 2 < NT){
      int k0 = (kt + 2) << 6;
      #pragma unroll
      for (int c=0;c<4;c++) gload_lds16(gA + (size_t)c*64*K + k0, &lbuf[stg][c*4096 + wave*512]);
      #pragma unroll
      for (int c=0;c<2;c++) gload_lds16(gW + (size_t)c*64*K + k0, &lbuf[stg][16384 + c*4096 + wave*512]);
    }
    const ushort* ab = &lbuf[cur][0];
    const ushort* bb = &lbuf[cur][16384];
    __builtin_amdgcn_s_setprio(1);
    #pragma unroll
    for (int ks=0; ks<2; ks++){
      short8 af[8], bfr[2];
      #pragma unroll
      for (int m=0;m<8;m++){
        int row = wrow*128 + m*16 + r16;
        af[m] = *(const short8*)&ab[row*64 + (((ks<<2)+g) ^ (row & 7))*8];
      }
      #pragma unroll
      for (int n=0;n<2;n++){
        int row = wcol*32 + n*16 + r16;
        bfr[n] = *(const short8*)&bb[row*64 + (((ks<<2)+g) ^ (row & 7))*8];
      }
      #pragma unroll
      for (int m=0;m<8;m++)
        #pragma unroll
        for (int n=0;n<2;n++)
          acc[m][n] = __builtin_amdgcn_mfma_f32_16x16x32_bf16(af[m], bfr[n], acc[m][n], 0, 0, 0);
    }
    __builtin_amdgcn_s_setprio(0);
    if (kt + 1 < NT){
      if (kt + 2 < NT) asm volatile("s_waitcnt vmcnt(6)" ::: "memory");
      else             asm volatile("s_waitcnt vmcnt(0)" ::: "memory");
      __builtin_amdgcn_s_barrier();
    }
    cur = (cur == 2) ? 0 : cur + 1;
    stg = (stg == 2) ? 0 : stg + 1;
  }

  // ---- epilogue ----
  if constexpr (MODE == 0 || MODE == 3){
    __syncthreads();
    ushort* ct = &lbuf[0][0];   // 256x128 bf16 = 64KB
    #pragma unroll
    for (int m=0;m<8;m++){
      #pragma unroll
      for (int n=0;n<2;n++){
        int col = wcol*32 + n*16 + r16;
        int gc = colBase + col;
        #pragma unroll
        for (int j=0;j<4;j++){
          int row = wrow*128 + m*16 + g*4 + j;
          float c = acc[m][n][j];
          ushort val;
          if constexpr (MODE == 0){
            int gr = rowBase + row;
            size_t o = (size_t)gr * N + gc;
            float s = 1.0f/(1.0f + __expf(-c));
            val = f2bf(s * res[o] + spk[o] + pe[(gr & (Ln-1))*Dn + gc]);
          } else {
            val = f2bf(gelu_fast(c + bias[gc]));
          }
          ct[row*128 + (col ^ ((row & 7) << 3))] = val;
        }
      }
    }
    __syncthreads();
    int r = t >> 1, ch = (t & 1)*64;
    ushort* dst = outb + (size_t)(rowBase + r)*N + colBase + ch;
    #pragma unroll
    for (int q=0;q<8;q++){
      int col = (ch + q*8) ^ ((r & 7) << 3);
      *(short8*)(dst + q*8) = *(const short8*)&ct[r*128 + col];
    }
  } else {
    #pragma unroll
    for (int m=0;m<8;m++){
      #pragma unroll
      for (int n=0;n<2;n++){
        int gc = colBase + wcol*32 + n*16 + r16;
        #pragma unroll
        for (int j=0;j<4;j++){
          int gr = rowBase + wrow*128 + m*16 + g*4 + j;
          size_t o = (size_t)gr * N + gc;
          float c = acc[m][n][j];
          if constexpr (MODE == 2){
            outf[o] = c + bias[gc] + bf2f(rbf[o]);
          } else {
            outf[o] = gelu_fast(c + bias[gc]) + res[o];
          }
        }
      }
    }
  }
}

// ---------------- GEMM B (R8): BM=BN=256, BK=64, dbuf, vmcnt(8) 2-barrier ----------------
// Used for ff1 (512 blocks = 2.0 balanced waves). MODE: 3 gelu->bf16
template<int MODE>
__global__ __launch_bounds__(512) void gemm256_kernel(
    const ushort* __restrict__ A, const ushort* __restrict__ W,
    const float* __restrict__ bias,
    ushort* __restrict__ outb, ushort* __restrict__ outb2,
    int K, int N, int gx)
{
  __shared__ ushort lbuf[2][2][16384];   // [dbuf][A/W][256 rows x 64 cols]
  int t = threadIdx.x;
  int wave = t >> 6, lane = t & 63;
  int wrow = wave >> 2, wcol = wave & 3;
  int g = lane >> 4, r16 = lane & 15;

  int nwg = gx * (Mn/256);
  int wg = blockIdx.x;
  int tile = (wg & 7)*(nwg >> 3) + (wg >> 3);
  int trow = tile / gx;
  int tcol = tile - trow*gx;
  int rowBase = trow * 256;
  int colBase = tcol * 256;

  int srow8 = lane >> 3;
  int sucol = ((lane & 7) ^ srow8) * 8;
  const ushort* gA = A + (size_t)(rowBase + wave*8 + srow8)*K + sucol;
  const ushort* gW = W + (size_t)(colBase + wave*8 + srow8)*K + sucol;

  f32x4 acc[8][4];
  #pragma unroll
  for (int m=0;m<8;m++)
    #pragma unroll
    for (int n=0;n<4;n++) acc[m][n] = (f32x4)0.0f;

  #pragma unroll
  for (int c=0;c<4;c++){
    gload_lds16(gA + (size_t)c*64*K, &lbuf[0][0][c*4096 + wave*512]);
    gload_lds16(gW + (size_t)c*64*K, &lbuf[0][1][c*4096 + wave*512]);
  }

  int cb = 0;
  for (int k0 = 0; k0 < K; k0 += 64){
    if (k0 + 64 < K){
      #pragma unroll
      for (int c=0;c<4;c++){
        gload_lds16(gA + (size_t)c*64*K + k0 + 64, &lbuf[cb^1][0][c*4096 + wave*512]);
        gload_lds16(gW + (size_t)c*64*K + k0 + 64, &lbuf[cb^1][1][c*4096 + wave*512]);
      }
      asm volatile("s_waitcnt vmcnt(8)" ::: "memory");
    } else {
      asm volatile("s_waitcnt vmcnt(0)" ::: "memory");
    }
    __builtin_amdgcn_s_barrier();
    #pragma unroll
    for (int ks=0; ks<2; ks++){
      short8 af[8], bfr[4];
      #pragma unroll
      for (int m=0;m<8;m++){
        int row = wrow*128 + m*16 + r16;
        af[m] = *(const short8*)&lbuf[cb][0][row*64 + (((ks<<2)+g) ^ (r16 & 7))*8];
      }
      #pragma unroll
      for (int n=0;n<4;n++){
        int row = wcol*64 + n*16 + r16;
        bfr[n] = *(const short8*)&lbuf[cb][1][row*64 + (((ks<<2)+g) ^ (r16 & 7))*8];
      }
      #pragma unroll
      for (int m=0;m<8;m++)
        #pragma unroll
        for (int n=0;n<4;n++)
          acc[m][n] = __builtin_amdgcn_mfma_f32_16x16x32_bf16(af[m], bfr[n], acc[m][n], 0, 0, 0);
    }
    __builtin_amdgcn_s_barrier();
    cb ^= 1;
  }

  ushort* ct = &lbuf[0][0][0];   // 256x256 bf16 = 128KB
  #pragma unroll
  for (int m=0;m<8;m++){
    #pragma unroll
    for (int n=0;n<4;n++){
      int col = wcol*64 + n*16 + r16;
      int gc = colBase + col;
      #pragma unroll
      for (int j=0;j<4;j++){
        int row = wrow*128 + m*16 + g*4 + j;
        ct[row*256 + (col ^ ((row & 7) << 3))] = f2bf(gelu_fast(acc[m][n][j] + bias[gc]));
      }
    }
  }
  __syncthreads();
  int r = t >> 1, ch = (t & 1)*128;
  ushort* dst = outb + (size_t)(rowBase + r)*N + colBase + ch;
  #pragma unroll
  for (int q=0;q<16;q++){
    int col = (ch + q*8) ^ ((r & 7) << 3);
    *(short8*)(dst + q*8) = *(const short8*)&ct[r*256 + col];
  }
  (void)outb2;
}

// ---------------- GEMM C (new): BM=128, BN=256, BK=64, 3-ring — qkv only ----------------
// grid = (M/128)*(N/256) = 128*6 = 768 blocks = 3.0 BALANCED occupancy-waves (vs 1.5 at 256²).
// Same R9 3-ring skeleton: 6 loads/wave/tile (A 2 chunks, B 4 chunks), vmcnt(6),
// 1 barrier/K-tile. 8 waves 2x4, wave tile 64x64, acc[4][4]. LDS 3x48KB.
// MODE 1: qk -> swizzled C-tile coalesced; V -> transposed outb2.
__global__ __launch_bounds__(512) void gemm128_kernel(
    const ushort* __restrict__ A, const ushort* __restrict__ W,
    const float* __restrict__ bias,
    ushort* __restrict__ outb, ushort* __restrict__ outb2,
    int K, int N, int gx)
{
  __shared__ ushort lbuf[3][24576];   // per buf: A 128x64 (8192) | B 256x64 (16384)
  int t = threadIdx.x;
  int wave = t >> 6, lane = t & 63;
  int wrow = wave >> 2, wcol = wave & 3;   // 2x4, wave tile 64x64
  int g = lane >> 4, r16 = lane & 15;

  int nwg = gx * (Mn/128);   // 6*128 = 768, %8==0
  int wg = blockIdx.x;
  int tile = (wg & 7)*(nwg >> 3) + (wg >> 3);
  int trow = tile / gx;
  int tcol = tile - trow*gx;
  int rowBase = trow * 128;
  int colBase = tcol * 256;

  int srow8 = lane >> 3;
  int sucol = ((lane & 7) ^ srow8) * 8;
  const ushort* gA = A + (size_t)(rowBase + wave*8 + srow8)*K + sucol;
  const ushort* gW = W + (size_t)(colBase + wave*8 + srow8)*K + sucol;

  int NT = K >> 6;

  f32x4 acc[4][4];
  #pragma unroll
  for (int m=0;m<4;m++)
    #pragma unroll
    for (int n=0;n<4;n++) acc[m][n] = (f32x4)0.0f;

  // prologue: kt=0 -> buf0, kt=1 -> buf1 (6 loads each: A c=0..1, B c=0..3)
  #pragma unroll
  for (int c=0;c<2;c++) gload_lds16(gA + (size_t)c*64*K,      &lbuf[0][c*4096 + wave*512]);
  #pragma unroll
  for (int c=0;c<4;c++) gload_lds16(gW + (size_t)c*64*K,      &lbuf[0][8192 + c*4096 + wave*512]);
  #pragma unroll
  for (int c=0;c<2;c++) gload_lds16(gA + (size_t)c*64*K + 64, &lbuf[1][c*4096 + wave*512]);
  #pragma unroll
  for (int c=0;c<4;c++) gload_lds16(gW + (size_t)c*64*K + 64, &lbuf[1][8192 + c*4096 + wave*512]);
  asm volatile("s_waitcnt vmcnt(6)" ::: "memory");
  __builtin_amdgcn_s_barrier();

  int cur = 0, stg = 2;
  for (int kt = 0; kt < NT; ++kt){
    if (kt + 2 < NT){
      int k0 = (kt + 2) << 6;
      #pragma unroll
      for (int c=0;c<2;c++) gload_lds16(gA + (size_t)c*64*K + k0, &lbuf[stg][c*4096 + wave*512]);
      #pragma unroll
      for (int c=0;c<4;c++) gload_lds16(gW + (size_t)c*64*K + k0, &lbuf[stg][8192 + c*4096 + wave*512]);
    }
    const ushort* ab = &lbuf[cur][0];
    const ushort* bb = &lbuf[cur][8192];
    __builtin_amdgcn_s_setprio(1);
    #pragma unroll
    for (int ks=0; ks<2; ks++){
      short8 af[4], bfr[4];
      #pragma unroll
      for (int m=0;m<4;m++){
        int row = wrow*64 + m*16 + r16;
        af[m] = *(const short8*)&ab[row*64 + (((ks<<2)+g) ^ (row & 7))*8];
      }
      #pragma unroll
      for (int n=0;n<4;n++){
        int row = wcol*64 + n*16 + r16;
        bfr[n] = *(const short8*)&bb[row*64 + (((ks<<2)+g) ^ (row & 7))*8];
      }
      #pragma unroll
      for (int m=0;m<4;m++)
        #pragma unroll
        for (int n=0;n<4;n++)
          acc[m][n] = __builtin_amdgcn_mfma_f32_16x16x32_bf16(af[m], bfr[n], acc[m][n], 0, 0, 0);
    }
    __builtin_amdgcn_s_setprio(0);
    if (kt + 1 < NT){
      if (kt + 2 < NT) asm volatile("s_waitcnt vmcnt(6)" ::: "memory");
      else             asm volatile("s_waitcnt vmcnt(0)" ::: "memory");
      __builtin_amdgcn_s_barrier();
    }
    cur = (cur == 2) ? 0 : cur + 1;
    stg = (stg == 2) ? 0 : stg + 1;
  }

  // ---- epilogue ----
  bool vpart = (colBase >= 1024);
  if (!vpart){
    __syncthreads();
    ushort* ct = &lbuf[0][0];   // 128x256 bf16 = 64KB
    #pragma unroll
    for (int m=0;m<4;m++){
      #pragma unroll
      for (int n=0;n<4;n++){
        int col = wcol*64 + n*16 + r16;
        int gc = colBase + col;
        float sc = (gc < 512) ? 0.125f : 1.0f;
        #pragma unroll
        for (int j=0;j<4;j++){
          int row = wrow*64 + m*16 + g*4 + j;
          ct[row*256 + (col ^ ((row & 7) << 3))] = f2bf((acc[m][n][j] + bias[gc]) * sc);
        }
      }
    }
    __syncthreads();
    int r = t >> 2, ch = (t & 3)*64;
    ushort* dst = outb + (size_t)(rowBase + r)*N + colBase + ch;
    #pragma unroll
    for (int q=0;q<8;q++){
      int col = (ch + q*8) ^ ((r & 7) << 3);
      *(short8*)(dst + q*8) = *(const short8*)&ct[r*256 + col];
    }
  } else {
    #pragma unroll
    for (int m=0;m<4;m++){
      #pragma unroll
      for (int n=0;n<4;n++){
        int gc = colBase + wcol*64 + n*16 + r16;
        int dhg = gc - 1024;
        int gr0 = rowBase + wrow*64 + m*16 + g*4;
        int bb2 = gr0 >> 9, l0 = gr0 & 511;
        ushort4 o4;
        o4.x = f2bf(acc[m][n][0] + bias[gc]);
        o4.y = f2bf(acc[m][n][1] + bias[gc]);
        o4.z = f2bf(acc[m][n][2] + bias[gc]);
        o4.w = f2bf(acc[m][n][3] + bias[gc]);
        *(ushort4*)(outb2 + ((size_t)(bb2*Hn + (dhg>>6))*DHn + (dhg & 63))*Ln + l0) = o4;
      }
    }
  }
}

// ---------------- MFMA flash attention: 8 waves x 32 q-rows (256 rows/block) ----------------
__global__ __launch_bounds__(512) void attn_mfma_kernel(
    const ushort* __restrict__ qb, const ushort* __restrict__ kb, const ushort* __restrict__ vtb,
    const int* __restrict__ mask, ushort* __restrict__ ctxb)
{
  __shared__ ushort lK[2][64][72];
  __shared__ ushort lVt[2][64][72];
  __shared__ ushort lP[8][32][72];

  int t = threadIdx.x;
  int w = t >> 6, lane = t & 63;
  int g = lane >> 4, r16 = lane & 15;
  int b = blockIdx.z, h = blockIdx.y;
  int qbase = blockIdx.x*256 + w*32;

  int key0 = t >> 3;
  int c8s = (t & 7) * 8;
  const ushort* kbase = kb + (size_t)(b*Ln)*QKVS + h*DHn + c8s;
  const ushort* vt = vtb + (size_t)((b*Hn + h)*DHn) * Ln;   // [dh][key]

  short8 af_q[2][2];
  #pragma unroll
  for (int m=0;m<2;m++)
    #pragma unroll
    for (int ks=0;ks<2;ks++)
      af_q[m][ks] = *(const short8*)(qb + (size_t)(b*Ln + qbase + m*16 + r16)*QKVS + h*DHn + ks*32 + g*8);

  f32x4 acc_ctx[2][4];
  #pragma unroll
  for (int m=0;m<2;m++)
    #pragma unroll
    for (int n=0;n<4;n++) acc_ctx[m][n] = (f32x4)0.0f;
  float mrun[2][4], lrun[2][4];
  #pragma unroll
  for (int m=0;m<2;m++)
    #pragma unroll
    for (int j=0;j<4;j++){ mrun[m][j] = -INFINITY; lrun[m][j] = 0.0f; }

  {
    short8 ka = *(const short8*)(kbase + (size_t)key0*QKVS);
    short8 va = *(const short8*)(vt + (size_t)key0*Ln + c8s);
    *(short8*)&lK[0][key0][c8s] = ka;
    *(short8*)&lVt[0][key0][c8s] = va;
  }
  __syncthreads();
  int cb = 0;

  for (int kb0 = 0; kb0 < Ln; kb0 += 64){
    short8 kna, vna;
    bool more = (kb0 + 64 < Ln);
    if (more){
      kna = *(const short8*)(kbase + (size_t)(kb0 + 64 + key0)*QKVS);
      vna = *(const short8*)(vt + (size_t)key0*Ln + kb0 + 64 + c8s);
    }

    // S = Q @ K^T
    f32x4 acc_s[2][4];
    #pragma unroll
    for (int m=0;m<2;m++)
      #pragma unroll
      for (int n=0;n<4;n++) acc_s[m][n] = (f32x4)0.0f;
    __builtin_amdgcn_s_setprio(1);
    #pragma unroll
    for (int ks=0;ks<2;ks++){
      short8 bf_k[4];
      #pragma unroll
      for (int n=0;n<4;n++)
        bf_k[n] = *(const short8*)&lK[cb][n*16 + r16][ks*32 + g*8];
      #pragma unroll
      for (int m=0;m<2;m++)
        #pragma unroll
        for (int n=0;n<4;n++)
          acc_s[m][n] = __builtin_amdgcn_mfma_f32_16x16x32_bf16(af_q[m][ks], bf_k[n], acc_s[m][n], 0, 0, 0);
    }
    __builtin_amdgcn_s_setprio(0);

    // mask keys
    #pragma unroll
    for (int n=0;n<4;n++){
      if (mask[b*Ln + kb0 + n*16 + r16] == 0){
        #pragma unroll
        for (int m=0;m<2;m++)
          #pragma unroll
          for (int j=0;j<4;j++) acc_s[m][n][j] = -1e10f;
      }
    }

    // online softmax; P -> bf16 in wave-private LDS
    #pragma unroll
    for (int m=0;m<2;m++){
      #pragma unroll
      for (int j=0;j<4;j++){
        float tmax = fmaxf(fmaxf(acc_s[m][0][j], acc_s[m][1][j]),
                           fmaxf(acc_s[m][2][j], acc_s[m][3][j]));
        #pragma unroll
        for (int off=1; off<16; off<<=1) tmax = fmaxf(tmax, __shfl_xor(tmax, off));
        float newm = fmaxf(mrun[m][j], tmax);
        float alpha = __expf(mrun[m][j] - newm);
        float p0 = __expf(acc_s[m][0][j] - newm);
        float p1 = __expf(acc_s[m][1][j] - newm);
        float p2 = __expf(acc_s[m][2][j] - newm);
        float p3 = __expf(acc_s[m][3][j] - newm);
        float tsum = (p0+p1)+(p2+p3);
        #pragma unroll
        for (int off=1; off<16; off<<=1) tsum += __shfl_xor(tsum, off);
        lrun[m][j] = lrun[m][j]*alpha + tsum;
        mrun[m][j] = newm;
        #pragma unroll
        for (int n2=0;n2<4;n2++) acc_ctx[m][n2][j] *= alpha;
        int prow = m*16 + g*4 + j;
        lP[w][prow][0*16 + r16] = f2bf(p0);
        lP[w][prow][1*16 + r16] = f2bf(p1);
        lP[w][prow][2*16 + r16] = f2bf(p2);
        lP[w][prow][3*16 + r16] = f2bf(p3);
      }
    }

    // ctx += P @ V
    __builtin_amdgcn_s_setprio(1);
    #pragma unroll
    for (int ks2=0;ks2<2;ks2++){
      short8 af_p[2], bf_v[4];
      #pragma unroll
      for (int m=0;m<2;m++)
        af_p[m] = *(const short8*)&lP[w][m*16 + r16][ks2*32 + g*8];
      #pragma unroll
      for (int n=0;n<4;n++)
        bf_v[n] = *(const short8*)&lVt[cb][n*16 + r16][ks2*32 + g*8];
      #pragma unroll
      for (int m=0;m<2;m++)
        #pragma unroll
        for (int n=0;n<4;n++)
          acc_ctx[m][n] = __builtin_amdgcn_mfma_f32_16x16x32_bf16(af_p[m], bf_v[n], acc_ctx[m][n], 0, 0, 0);
    }
    __builtin_amdgcn_s_setprio(0);

    if (more){
      *(short8*)&lK[cb^1][key0][c8s] = kna;
      *(short8*)&lVt[cb^1][key0][c8s] = vna;
    }
    __syncthreads();
    cb ^= 1;
  }

  #pragma unroll
  for (int m=0;m<2;m++){
    #pragma unroll
    for (int j=0;j<4;j++){
      float inv = 1.0f / lrun[m][j];
      int gr = qbase + m*16 + g*4 + j;
      #pragma unroll
      for (int n=0;n<4;n++){
        ctxb[(size_t)(b*Ln + gr)*Dn + h*DHn + n*16 + r16] = f2bf(acc_ctx[m][n][j] * inv);
      }
    }
  }
}

// ---------------- layernorm: one wave per row (D=512), out bf16 ----------------
__global__ __launch_bounds__(256) void ln_kernel(
    const float* __restrict__ hbuf, const float* __restrict__ gamma, const float* __restrict__ beta,
    ushort* __restrict__ out)
{
  int row = blockIdx.x*4 + (threadIdx.x >> 6);
  int lane = threadIdx.x & 63;
  const float* p = hbuf + (size_t)row*Dn + lane*8;
  float4 a = *(const float4*)p;
  float4 c = *(const float4*)(p + 4);
  float v[8] = {a.x,a.y,a.z,a.w,c.x,c.y,c.z,c.w};
  float s = 0.f, ss = 0.f;
  #pragma unroll
  for (int j=0;j<8;j++){ s += v[j]; ss += v[j]*v[j]; }
  #pragma unroll
  for (int off=32; off>0; off>>=1){ s += __shfl_xor(s, off); ss += __shfl_xor(ss, off); }
  float mu = s * (1.0f/Dn);
  float var = ss * (1.0f/Dn) - mu*mu;
  float rstd = rsqrtf(var + 1e-5f);
  ushort o8[8];
  #pragma unroll
  for (int j=0;j<8;j++) o8[j] = f2bf((v[j]-mu)*rstd*gamma[lane*8+j] + beta[lane*8+j]);
  ushort* op = out + (size_t)row*Dn + lane*8;
  *(ushort4*)op       = make_ushort4(o8[0],o8[1],o8[2],o8[3]);
  *(ushort4*)(op + 4) = make_ushort4(o8[4],o8[5],o8[6],o8[7]);
}

extern "C" void kernel_launch(void* const* d_in, const int* in_sizes, int n_in,
                              void* d_out, int out_size, void* d_ws, size_t ws_size,
                              hipStream_t stream) {
  (void)in_sizes; (void)n_in; (void)out_size; (void)ws_size;
  const float* x    = (const float*)d_in[0];
  const int*   mask = (const int*)d_in[1];
  const float* spk  = (const float*)d_in[2];
  const float* Wg   = (const float*)d_in[3];
  const float* Wq   = (const float*)d_in[4];  const float* bq = (const float*)d_in[5];
  const float* Wk   = (const float*)d_in[6];  const float* bk = (const float*)d_in[7];
  const float* Wv   = (const float*)d_in[8];  const float* bv = (const float*)d_in[9];
  const float* Wo   = (const float*)d_in[10]; const float* bo = (const float*)d_in[11];
  const float* lng  = (const float*)d_in[12]; const float* lnbeta = (const float*)d_in[13];
  const float* W1   = (const float*)d_in[14]; const float* b1 = (const float*)d_in[15];
  const float* W2   = (const float*)d_in[16]; const float* b2 = (const float*)d_in[17];
  float* out = (float*)d_out;

  char* w = (char*)d_ws;
  size_t o = 0;
  ushort* xbf   = (ushort*)(w + o); o += (size_t)Mn*Dn*2;    // dead after gate   } overlapped
  ushort* xinb  = (ushort*)(w + o); o += (size_t)Mn*Dn*2;    // dead after Wo     } by midb
  ushort* qkvb  = (ushort*)(w + o); o += (size_t)Mn*QKVS*2;  // dead after attn   }
  ushort* vtb   = (ushort*)(w + o); o += (size_t)Mn*Dn*2;    // V transposed [(b,h,dh)][key]
  ushort* ctxb  = (ushort*)(w + o); o += (size_t)Mn*Dn*2;
  float*  hbuf  = (float*)(w + o);  o += (size_t)Mn*Dn*4;
  ushort* lnbuf = (ushort*)(w + o); o += (size_t)Mn*Dn*2;
  ushort* wgb   = (ushort*)(w + o); o += (size_t)Dn*Dn*2;
  ushort* wqkvb = (ushort*)(w + o); o += (size_t)QKVS*Dn*2;
  ushort* wob   = (ushort*)(w + o); o += (size_t)Dn*Dn*2;
  ushort* w1b   = (ushort*)(w + o); o += (size_t)FFn*Dn*2;
  ushort* w2b   = (ushort*)(w + o); o += (size_t)Dn*FFn*2;
  float*  pebuf = (float*)(w + o);  o += (size_t)Ln*Dn*4;
  float*  bqkv  = (float*)(w + o);  o += (size_t)QKVS*4;
  ushort* midb  = xbf;  // M x FF bf16 (64MB), overlaps xbf+xinb+qkvb (all dead by ff1)

  // fused prep: x cvt + all weight cvts + PE + bias pack (one launch)
  hipLaunchKernelGGL(prep_kernel, dim3(11778), dim3(256), 0, stream,
                     x, xbf, Wg, Wq, Wk, Wv, Wo, W1, W2, bq, bk, bv,
                     wgb, wqkvb, wob, w1b, w2b, pebuf, bqkv);

  // gate: xin = sigmoid(x@Wg^T)*x + spk + pe  -> xinb (bf16 only)
  hipLaunchKernelGGL((gemm_kernel<0>), dim3((Dn/128)*(Mn/256)), dim3(512), 0, stream,
                     xbf, wgb, (const float*)nullptr, x, (const ushort*)nullptr, spk, pebuf,
                     (float*)nullptr, xinb, (ushort*)nullptr, Dn, Dn, Dn/128);
  // fused qkv (128x256 tile, 768 balanced blocks): q,k -> qkvb[M][1536]; v -> vtb transposed
  hipLaunchKernelGGL(gemm128_kernel, dim3((QKVS/256)*(Mn/128)), dim3(512), 0, stream,
                     xinb, wqkvb, bqkv, qkvb, vtb, Dn, QKVS, QKVS/256);
  // attention (MFMA flash, 8-wave blocks)
  hipLaunchKernelGGL(attn_mfma_kernel, dim3(Ln/256, Hn, Bn), dim3(512), 0, stream,
                     qkvb, qkvb + 512, vtb, mask, ctxb);
  // h = ctx@Wo^T + bo + xin(bf16)
  hipLaunchKernelGGL((gemm_kernel<2>), dim3((Dn/128)*(Mn/256)), dim3(512), 0, stream,
                     ctxb, wob, bo, (const float*)nullptr, xinb, (const float*)nullptr,
                     (const float*)nullptr, hbuf, (ushort*)nullptr, (ushort*)nullptr, Dn, Dn, Dn/128);
  // layernorm
  hipLaunchKernelGGL(ln_kernel, dim3(Mn/4), dim3(256), 0, stream, hbuf, lng, lnbeta, lnbuf);
  // mid = gelu(ln@W1^T + b1)  (256² tile, 512 balanced blocks)
  hipLaunchKernelGGL((gemm256_kernel<3>), dim3((FFn/256)*(Mn/256)), dim3(512), 0, stream,
                     lnbuf, w1b, b1, midb, (ushort*)nullptr, Dn, FFn, FFn/256);
  // out = gelu(mid@W2^T + b2) + h
  hipLaunchKernelGGL((gemm_kernel<4>), dim3((Dn/128)*(Mn/256)), dim3(512), 0, stream,
                     midb, w2b, b2, hbuf, (const ushort*)nullptr,
                     (const float*)nullptr, (const float*)nullptr,
                     out, (ushort*)nullptr, (ushort*)nullptr, FFn, Dn, Dn/128);
}

// Round 13
// 296.190 us; speedup vs baseline: 1.0252x; 1.0252x over previous
//
#include <hip/hip_runtime.h>
#include <math.h>

#define Bn 32
#define Ln 512
#define Dn 512
#define Hn 8
#define DHn 64
#define FFn 2048
#define Mn (Bn*Ln)   // 16384
#define QKVS 1536

typedef __attribute__((ext_vector_type(4))) float f32x4;
typedef __attribute__((ext_vector_type(8))) short short8;

__device__ __forceinline__ float bf2f(ushort u){ return __uint_as_float(((unsigned)u) << 16); }
__device__ __forceinline__ ushort f2bf(float f){
  unsigned u = __float_as_uint(f);
  u += 0x7FFFu + ((u >> 16) & 1u);
  return (ushort)(u >> 16);
}
// exact sigmoid-form of tanh-gelu: 0.5x(1+tanh(y)) == x*sigmoid(2y)
__device__ __forceinline__ float gelu_fast(float x){
  float y2 = 1.5957691216057308f * (x + 0.044715f*x*x*x);
  return x / (1.0f + __expf(-y2));
}

// async global->LDS, 16B per lane; LDS dest is wave-uniform base + lane*16
__device__ __forceinline__ void gload_lds16(const ushort* g, ushort* l){
  __builtin_amdgcn_global_load_lds(
      (__attribute__((address_space(1))) void*)(void*)g,
      (__attribute__((address_space(3))) void*)(void*)l, 16, 0, 0);
}

__device__ __forceinline__ void cvt4(const float* __restrict__ in, ushort* __restrict__ out, int u){
  float4 v = *(const float4*)(in + u*4);
  ushort4 o;
  o.x = f2bf(v.x); o.y = f2bf(v.y); o.z = f2bf(v.z); o.w = f2bf(v.w);
  *(ushort4*)(out + u*4) = o;
}

// ---------------- fused prep: x cvt + 7 weight cvts + PE table + qkv bias pack ----------------
__global__ __launch_bounds__(256) void prep_kernel(
    const float* __restrict__ x, ushort* __restrict__ xbf,
    const float* __restrict__ Wg, const float* __restrict__ Wq, const float* __restrict__ Wk,
    const float* __restrict__ Wv, const float* __restrict__ Wo, const float* __restrict__ W1,
    const float* __restrict__ W2,
    const float* __restrict__ bq, const float* __restrict__ bk, const float* __restrict__ bv,
    ushort* __restrict__ wgb, ushort* __restrict__ wqkvb, ushort* __restrict__ wob,
    ushort* __restrict__ w1b, ushort* __restrict__ w2b,
    float* __restrict__ pe, float* __restrict__ bqkv)
{
  int u = blockIdx.x*256 + threadIdx.x;
  const int XU = 2097152, WU = 65536, FU = 262144;
  if (u < XU){ cvt4(x, xbf, u); return; }             u -= XU;
  if (u < WU){ cvt4(Wg, wgb, u); return; }            u -= WU;
  if (u < WU){ cvt4(Wq, wqkvb, u); return; }          u -= WU;
  if (u < WU){ cvt4(Wk, wqkvb + 262144, u); return; } u -= WU;
  if (u < WU){ cvt4(Wv, wqkvb + 524288, u); return; } u -= WU;
  if (u < WU){ cvt4(Wo, wob, u); return; }            u -= WU;
  if (u < FU){ cvt4(W1, w1b, u); return; }            u -= FU;
  if (u < FU){ cvt4(W2, w2b, u); return; }            u -= FU;
  if (u < WU){                                        // PE table
    int e = u*4; int l = e >> 9; int d0 = e & 511;
    #pragma unroll
    for (int p=0;p<2;p++){
      int i = (d0 >> 1) + p;
      float dv = expf((float)(2*i) * (-9.210340371976184f/512.0f));
      float ang = (float)l * dv;
      pe[e + 2*p]     = sinf(ang);
      pe[e + 2*p + 1] = cosf(ang);
    }
    return;
  }
  u -= WU;
  if (u < 384){
    int e = u*4;
    #pragma unroll
    for (int j=0;j<4;j++){
      int i = e + j;
      bqkv[i] = (i < 512) ? bq[i] : (i < 1024) ? bk[i-512] : bv[i-1024];
    }
  }
}

// ---------------- GEMM A (R9): BM=256, BN=128, BK=64, 3-ring, 1 barrier/K-tile ----------------
// MODE: 0 gate (sigmoid(c)*bf16res + spk + pe -> bf16)
//       2 c + bias + bf16res -> bf16 (h)
//       4 gelu + bf16res -> f32 (final out)
template<int MODE>
__global__ __launch_bounds__(512) void gemm_kernel(
    const ushort* __restrict__ A, const ushort* __restrict__ W,
    const float* __restrict__ bias,
    const ushort* __restrict__ rbf,
    const float* __restrict__ spk, const float* __restrict__ pe,
    float* __restrict__ outf, ushort* __restrict__ outb,
    int K, int N, int gx)
{
  __shared__ ushort lbuf[3][24576];   // per buf: A 256x64 (16384) | B 128x64 (8192)
  int t = threadIdx.x;
  int wave = t >> 6, lane = t & 63;
  int wrow = wave >> 2, wcol = wave & 3;
  int g = lane >> 4, r16 = lane & 15;

  int nwg = gx * (Mn/256);
  int wg = blockIdx.x;
  int tile = (wg & 7)*(nwg >> 3) + (wg >> 3);
  int trow = tile / gx;
  int tcol = tile - trow*gx;
  int rowBase = trow * 256;
  int colBase = tcol * 128;

  int srow8 = lane >> 3;
  int sucol = ((lane & 7) ^ srow8) * 8;
  const ushort* gA = A + (size_t)(rowBase + wave*8 + srow8)*K + sucol;
  const ushort* gW = W + (size_t)(colBase + wave*8 + srow8)*K + sucol;

  int NT = K >> 6;

  f32x4 acc[8][2];
  #pragma unroll
  for (int m=0;m<8;m++)
    #pragma unroll
    for (int n=0;n<2;n++) acc[m][n] = (f32x4)0.0f;

  #pragma unroll
  for (int c=0;c<4;c++) gload_lds16(gA + (size_t)c*64*K,      &lbuf[0][c*4096 + wave*512]);
  #pragma unroll
  for (int c=0;c<2;c++) gload_lds16(gW + (size_t)c*64*K,      &lbuf[0][16384 + c*4096 + wave*512]);
  #pragma unroll
  for (int c=0;c<4;c++) gload_lds16(gA + (size_t)c*64*K + 64, &lbuf[1][c*4096 + wave*512]);
  #pragma unroll
  for (int c=0;c<2;c++) gload_lds16(gW + (size_t)c*64*K + 64, &lbuf[1][16384 + c*4096 + wave*512]);
  asm volatile("s_waitcnt vmcnt(6)" ::: "memory");
  __builtin_amdgcn_s_barrier();

  int cur = 0, stg = 2;
  for (int kt = 0; kt < NT; ++kt){
    if (kt + 2 < NT){
      int k0 = (kt + 2) << 6;
      #pragma unroll
      for (int c=0;c<4;c++) gload_lds16(gA + (size_t)c*64*K + k0, &lbuf[stg][c*4096 + wave*512]);
      #pragma unroll
      for (int c=0;c<2;c++) gload_lds16(gW + (size_t)c*64*K + k0, &lbuf[stg][16384 + c*4096 + wave*512]);
    }
    const ushort* ab = &lbuf[cur][0];
    const ushort* bb = &lbuf[cur][16384];
    __builtin_amdgcn_s_setprio(1);
    #pragma unroll
    for (int ks=0; ks<2; ks++){
      short8 af[8], bfr[2];
      #pragma unroll
      for (int m=0;m<8;m++){
        int row = wrow*128 + m*16 + r16;
        af[m] = *(const short8*)&ab[row*64 + (((ks<<2)+g) ^ (row & 7))*8];
      }
      #pragma unroll
      for (int n=0;n<2;n++){
        int row = wcol*32 + n*16 + r16;
        bfr[n] = *(const short8*)&bb[row*64 + (((ks<<2)+g) ^ (row & 7))*8];
      }
      #pragma unroll
      for (int m=0;m<8;m++)
        #pragma unroll
        for (int n=0;n<2;n++)
          acc[m][n] = __builtin_amdgcn_mfma_f32_16x16x32_bf16(af[m], bfr[n], acc[m][n], 0, 0, 0);
    }
    __builtin_amdgcn_s_setprio(0);
    if (kt + 1 < NT){
      if (kt + 2 < NT) asm volatile("s_waitcnt vmcnt(6)" ::: "memory");
      else             asm volatile("s_waitcnt vmcnt(0)" ::: "memory");
      __builtin_amdgcn_s_barrier();
    }
    cur = (cur == 2) ? 0 : cur + 1;
    stg = (stg == 2) ? 0 : stg + 1;
  }

  // ---- epilogue ----
  if constexpr (MODE == 0 || MODE == 2){
    __syncthreads();
    ushort* ct = &lbuf[0][0];   // 256x128 bf16 = 64KB
    #pragma unroll
    for (int m=0;m<8;m++){
      #pragma unroll
      for (int n=0;n<2;n++){
        int col = wcol*32 + n*16 + r16;
        int gc = colBase + col;
        #pragma unroll
        for (int j=0;j<4;j++){
          int row = wrow*128 + m*16 + g*4 + j;
          int gr = rowBase + row;
          size_t o = (size_t)gr * N + gc;
          float c = acc[m][n][j];
          ushort val;
          if constexpr (MODE == 0){
            float s = 1.0f/(1.0f + __expf(-c));
            val = f2bf(s * bf2f(rbf[o]) + spk[o] + pe[(gr & (Ln-1))*Dn + gc]);
          } else {
            val = f2bf(c + bias[gc] + bf2f(rbf[o]));
          }
          ct[row*128 + (col ^ ((row & 7) << 3))] = val;
        }
      }
    }
    __syncthreads();
    int r = t >> 1, ch = (t & 1)*64;
    ushort* dst = outb + (size_t)(rowBase + r)*N + colBase + ch;
    #pragma unroll
    for (int q=0;q<8;q++){
      int col = (ch + q*8) ^ ((r & 7) << 3);
      *(short8*)(dst + q*8) = *(const short8*)&ct[r*128 + col];
    }
  } else {
    #pragma unroll
    for (int m=0;m<8;m++){
      #pragma unroll
      for (int n=0;n<2;n++){
        int gc = colBase + wcol*32 + n*16 + r16;
        #pragma unroll
        for (int j=0;j<4;j++){
          int gr = rowBase + wrow*128 + m*16 + g*4 + j;
          size_t o = (size_t)gr * N + gc;
          outf[o] = gelu_fast(acc[m][n][j] + bias[gc]) + bf2f(rbf[o]);
        }
      }
    }
  }
}

// ---------------- GEMM B (R8): BM=BN=256, BK=64, dbuf, vmcnt(8) 2-barrier ----------------
// Used for ff1 (512 blocks = 2.0 balanced waves). MODE 3: gelu->bf16
__global__ __launch_bounds__(512) void gemm256_kernel(
    const ushort* __restrict__ A, const ushort* __restrict__ W,
    const float* __restrict__ bias,
    ushort* __restrict__ outb,
    int K, int N, int gx)
{
  __shared__ ushort lbuf[2][2][16384];   // [dbuf][A/W][256 rows x 64 cols]
  int t = threadIdx.x;
  int wave = t >> 6, lane = t & 63;
  int wrow = wave >> 2, wcol = wave & 3;
  int g = lane >> 4, r16 = lane & 15;

  int nwg = gx * (Mn/256);
  int wg = blockIdx.x;
  int tile = (wg & 7)*(nwg >> 3) + (wg >> 3);
  int trow = tile / gx;
  int tcol = tile - trow*gx;
  int rowBase = trow * 256;
  int colBase = tcol * 256;

  int srow8 = lane >> 3;
  int sucol = ((lane & 7) ^ srow8) * 8;
  const ushort* gA = A + (size_t)(rowBase + wave*8 + srow8)*K + sucol;
  const ushort* gW = W + (size_t)(colBase + wave*8 + srow8)*K + sucol;

  f32x4 acc[8][4];
  #pragma unroll
  for (int m=0;m<8;m++)
    #pragma unroll
    for (int n=0;n<4;n++) acc[m][n] = (f32x4)0.0f;

  #pragma unroll
  for (int c=0;c<4;c++){
    gload_lds16(gA + (size_t)c*64*K, &lbuf[0][0][c*4096 + wave*512]);
    gload_lds16(gW + (size_t)c*64*K, &lbuf[0][1][c*4096 + wave*512]);
  }

  int cb = 0;
  for (int k0 = 0; k0 < K; k0 += 64){
    if (k0 + 64 < K){
      #pragma unroll
      for (int c=0;c<4;c++){
        gload_lds16(gA + (size_t)c*64*K + k0 + 64, &lbuf[cb^1][0][c*4096 + wave*512]);
        gload_lds16(gW + (size_t)c*64*K + k0 + 64, &lbuf[cb^1][1][c*4096 + wave*512]);
      }
      asm volatile("s_waitcnt vmcnt(8)" ::: "memory");
    } else {
      asm volatile("s_waitcnt vmcnt(0)" ::: "memory");
    }
    __builtin_amdgcn_s_barrier();
    #pragma unroll
    for (int ks=0; ks<2; ks++){
      short8 af[8], bfr[4];
      #pragma unroll
      for (int m=0;m<8;m++){
        int row = wrow*128 + m*16 + r16;
        af[m] = *(const short8*)&lbuf[cb][0][row*64 + (((ks<<2)+g) ^ (r16 & 7))*8];
      }
      #pragma unroll
      for (int n=0;n<4;n++){
        int row = wcol*64 + n*16 + r16;
        bfr[n] = *(const short8*)&lbuf[cb][1][row*64 + (((ks<<2)+g) ^ (r16 & 7))*8];
      }
      #pragma unroll
      for (int m=0;m<8;m++)
        #pragma unroll
        for (int n=0;n<4;n++)
          acc[m][n] = __builtin_amdgcn_mfma_f32_16x16x32_bf16(af[m], bfr[n], acc[m][n], 0, 0, 0);
    }
    __builtin_amdgcn_s_barrier();
    cb ^= 1;
  }

  ushort* ct = &lbuf[0][0][0];   // 256x256 bf16 = 128KB
  #pragma unroll
  for (int m=0;m<8;m++){
    #pragma unroll
    for (int n=0;n<4;n++){
      int col = wcol*64 + n*16 + r16;
      int gc = colBase + col;
      #pragma unroll
      for (int j=0;j<4;j++){
        int row = wrow*128 + m*16 + g*4 + j;
        ct[row*256 + (col ^ ((row & 7) << 3))] = f2bf(gelu_fast(acc[m][n][j] + bias[gc]));
      }
    }
  }
  __syncthreads();
  int r = t >> 1, ch = (t & 1)*128;
  ushort* dst = outb + (size_t)(rowBase + r)*N + colBase + ch;
  #pragma unroll
  for (int q=0;q<16;q++){
    int col = (ch + q*8) ^ ((r & 7) << 3);
    *(short8*)(dst + q*8) = *(const short8*)&ct[r*256 + col];
  }
}

// ---------------- GEMM C: BM=128, BN=256, BK=64, 3-ring — qkv only ----------------
// grid = 768 blocks = 3.0 balanced occupancy-waves.
__global__ __launch_bounds__(512) void gemm128_kernel(
    const ushort* __restrict__ A, const ushort* __restrict__ W,
    const float* __restrict__ bias,
    ushort* __restrict__ outb, ushort* __restrict__ outb2,
    int K, int N, int gx)
{
  __shared__ ushort lbuf[3][24576];   // per buf: A 128x64 (8192) | B 256x64 (16384)
  int t = threadIdx.x;
  int wave = t >> 6, lane = t & 63;
  int wrow = wave >> 2, wcol = wave & 3;   // 2x4, wave tile 64x64
  int g = lane >> 4, r16 = lane & 15;

  int nwg = gx * (Mn/128);   // 768, %8==0
  int wg = blockIdx.x;
  int tile = (wg & 7)*(nwg >> 3) + (wg >> 3);
  int trow = tile / gx;
  int tcol = tile - trow*gx;
  int rowBase = trow * 128;
  int colBase = tcol * 256;

  int srow8 = lane >> 3;
  int sucol = ((lane & 7) ^ srow8) * 8;
  const ushort* gA = A + (size_t)(rowBase + wave*8 + srow8)*K + sucol;
  const ushort* gW = W + (size_t)(colBase + wave*8 + srow8)*K + sucol;

  int NT = K >> 6;

  f32x4 acc[4][4];
  #pragma unroll
  for (int m=0;m<4;m++)
    #pragma unroll
    for (int n=0;n<4;n++) acc[m][n] = (f32x4)0.0f;

  #pragma unroll
  for (int c=0;c<2;c++) gload_lds16(gA + (size_t)c*64*K,      &lbuf[0][c*4096 + wave*512]);
  #pragma unroll
  for (int c=0;c<4;c++) gload_lds16(gW + (size_t)c*64*K,      &lbuf[0][8192 + c*4096 + wave*512]);
  #pragma unroll
  for (int c=0;c<2;c++) gload_lds16(gA + (size_t)c*64*K + 64, &lbuf[1][c*4096 + wave*512]);
  #pragma unroll
  for (int c=0;c<4;c++) gload_lds16(gW + (size_t)c*64*K + 64, &lbuf[1][8192 + c*4096 + wave*512]);
  asm volatile("s_waitcnt vmcnt(6)" ::: "memory");
  __builtin_amdgcn_s_barrier();

  int cur = 0, stg = 2;
  for (int kt = 0; kt < NT; ++kt){
    if (kt + 2 < NT){
      int k0 = (kt + 2) << 6;
      #pragma unroll
      for (int c=0;c<2;c++) gload_lds16(gA + (size_t)c*64*K + k0, &lbuf[stg][c*4096 + wave*512]);
      #pragma unroll
      for (int c=0;c<4;c++) gload_lds16(gW + (size_t)c*64*K + k0, &lbuf[stg][8192 + c*4096 + wave*512]);
    }
    const ushort* ab = &lbuf[cur][0];
    const ushort* bb = &lbuf[cur][8192];
    __builtin_amdgcn_s_setprio(1);
    #pragma unroll
    for (int ks=0; ks<2; ks++){
      short8 af[4], bfr[4];
      #pragma unroll
      for (int m=0;m<4;m++){
        int row = wrow*64 + m*16 + r16;
        af[m] = *(const short8*)&ab[row*64 + (((ks<<2)+g) ^ (row & 7))*8];
      }
      #pragma unroll
      for (int n=0;n<4;n++){
        int row = wcol*64 + n*16 + r16;
        bfr[n] = *(const short8*)&bb[row*64 + (((ks<<2)+g) ^ (row & 7))*8];
      }
      #pragma unroll
      for (int m=0;m<4;m++)
        #pragma unroll
        for (int n=0;n<4;n++)
          acc[m][n] = __builtin_amdgcn_mfma_f32_16x16x32_bf16(af[m], bfr[n], acc[m][n], 0, 0, 0);
    }
    __builtin_amdgcn_s_setprio(0);
    if (kt + 1 < NT){
      if (kt + 2 < NT) asm volatile("s_waitcnt vmcnt(6)" ::: "memory");
      else             asm volatile("s_waitcnt vmcnt(0)" ::: "memory");
      __builtin_amdgcn_s_barrier();
    }
    cur = (cur == 2) ? 0 : cur + 1;
    stg = (stg == 2) ? 0 : stg + 1;
  }

  // ---- epilogue ----
  bool vpart = (colBase >= 1024);
  if (!vpart){
    __syncthreads();
    ushort* ct = &lbuf[0][0];   // 128x256 bf16 = 64KB
    #pragma unroll
    for (int m=0;m<4;m++){
      #pragma unroll
      for (int n=0;n<4;n++){
        int col = wcol*64 + n*16 + r16;
        int gc = colBase + col;
        float sc = (gc < 512) ? 0.125f : 1.0f;
        #pragma unroll
        for (int j=0;j<4;j++){
          int row = wrow*64 + m*16 + g*4 + j;
          ct[row*256 + (col ^ ((row & 7) << 3))] = f2bf((acc[m][n][j] + bias[gc]) * sc);
        }
      }
    }
    __syncthreads();
    int r = t >> 2, ch = (t & 3)*64;
    ushort* dst = outb + (size_t)(rowBase + r)*N + colBase + ch;
    #pragma unroll
    for (int q=0;q<8;q++){
      int col = (ch + q*8) ^ ((r & 7) << 3);
      *(short8*)(dst + q*8) = *(const short8*)&ct[r*256 + col];
    }
  } else {
    #pragma unroll
    for (int m=0;m<4;m++){
      #pragma unroll
      for (int n=0;n<4;n++){
        int gc = colBase + wcol*64 + n*16 + r16;
        int dhg = gc - 1024;
        int gr0 = rowBase + wrow*64 + m*16 + g*4;
        int bb2 = gr0 >> 9, l0 = gr0 & 511;
        ushort4 o4;
        o4.x = f2bf(acc[m][n][0] + bias[gc]);
        o4.y = f2bf(acc[m][n][1] + bias[gc]);
        o4.z = f2bf(acc[m][n][2] + bias[gc]);
        o4.w = f2bf(acc[m][n][3] + bias[gc]);
        *(ushort4*)(outb2 + ((size_t)(bb2*Hn + (dhg>>6))*DHn + (dhg & 63))*Ln + l0) = o4;
      }
    }
  }
}

// ---------------- MFMA flash attention: 8 waves x 32 q-rows (256 rows/block) ----------------
__global__ __launch_bounds__(512) void attn_mfma_kernel(
    const ushort* __restrict__ qb, const ushort* __restrict__ kb, const ushort* __restrict__ vtb,
    const int* __restrict__ mask, ushort* __restrict__ ctxb)
{
  __shared__ ushort lK[2][64][72];
  __shared__ ushort lVt[2][64][72];
  __shared__ ushort lP[8][32][72];

  int t = threadIdx.x;
  int w = t >> 6, lane = t & 63;
  int g = lane >> 4, r16 = lane & 15;
  int b = blockIdx.z, h = blockIdx.y;
  int qbase = blockIdx.x*256 + w*32;

  int key0 = t >> 3;
  int c8s = (t & 7) * 8;
  const ushort* kbase = kb + (size_t)(b*Ln)*QKVS + h*DHn + c8s;
  const ushort* vt = vtb + (size_t)((b*Hn + h)*DHn) * Ln;   // [dh][key]

  short8 af_q[2][2];
  #pragma unroll
  for (int m=0;m<2;m++)
    #pragma unroll
    for (int ks=0;ks<2;ks++)
      af_q[m][ks] = *(const short8*)(qb + (size_t)(b*Ln + qbase + m*16 + r16)*QKVS + h*DHn + ks*32 + g*8);

  f32x4 acc_ctx[2][4];
  #pragma unroll
  for (int m=0;m<2;m++)
    #pragma unroll
    for (int n=0;n<4;n++) acc_ctx[m][n] = (f32x4)0.0f;
  float mrun[2][4], lrun[2][4];
  #pragma unroll
  for (int m=0;m<2;m++)
    #pragma unroll
    for (int j=0;j<4;j++){ mrun[m][j] = -INFINITY; lrun[m][j] = 0.0f; }

  {
    short8 ka = *(const short8*)(kbase + (size_t)key0*QKVS);
    short8 va = *(const short8*)(vt + (size_t)key0*Ln + c8s);
    *(short8*)&lK[0][key0][c8s] = ka;
    *(short8*)&lVt[0][key0][c8s] = va;
  }
  __syncthreads();
  int cb = 0;

  for (int kb0 = 0; kb0 < Ln; kb0 += 64){
    short8 kna, vna;
    bool more = (kb0 + 64 < Ln);
    if (more){
      kna = *(const short8*)(kbase + (size_t)(kb0 + 64 + key0)*QKVS);
      vna = *(const short8*)(vt + (size_t)key0*Ln + kb0 + 64 + c8s);
    }

    // S = Q @ K^T
    f32x4 acc_s[2][4];
    #pragma unroll
    for (int m=0;m<2;m++)
      #pragma unroll
      for (int n=0;n<4;n++) acc_s[m][n] = (f32x4)0.0f;
    __builtin_amdgcn_s_setprio(1);
    #pragma unroll
    for (int ks=0;ks<2;ks++){
      short8 bf_k[4];
      #pragma unroll
      for (int n=0;n<4;n++)
        bf_k[n] = *(const short8*)&lK[cb][n*16 + r16][ks*32 + g*8];
      #pragma unroll
      for (int m=0;m<2;m++)
        #pragma unroll
        for (int n=0;n<4;n++)
          acc_s[m][n] = __builtin_amdgcn_mfma_f32_16x16x32_bf16(af_q[m][ks], bf_k[n], acc_s[m][n], 0, 0, 0);
    }
    __builtin_amdgcn_s_setprio(0);

    // mask keys
    #pragma unroll
    for (int n=0;n<4;n++){
      if (mask[b*Ln + kb0 + n*16 + r16] == 0){
        #pragma unroll
        for (int m=0;m<2;m++)
          #pragma unroll
          for (int j=0;j<4;j++) acc_s[m][n][j] = -1e10f;
      }
    }

    // online softmax; P -> bf16 in wave-private LDS
    #pragma unroll
    for (int m=0;m<2;m++){
      #pragma unroll
      for (int j=0;j<4;j++){
        float tmax = fmaxf(fmaxf(acc_s[m][0][j], acc_s[m][1][j]),
                           fmaxf(acc_s[m][2][j], acc_s[m][3][j]));
        #pragma unroll
        for (int off=1; off<16; off<<=1) tmax = fmaxf(tmax, __shfl_xor(tmax, off));
        float newm = fmaxf(mrun[m][j], tmax);
        float alpha = __expf(mrun[m][j] - newm);
        float p0 = __expf(acc_s[m][0][j] - newm);
        float p1 = __expf(acc_s[m][1][j] - newm);
        float p2 = __expf(acc_s[m][2][j] - newm);
        float p3 = __expf(acc_s[m][3][j] - newm);
        float tsum = (p0+p1)+(p2+p3);
        #pragma unroll
        for (int off=1; off<16; off<<=1) tsum += __shfl_xor(tsum, off);
        lrun[m][j] = lrun[m][j]*alpha + tsum;
        mrun[m][j] = newm;
        #pragma unroll
        for (int n2=0;n2<4;n2++) acc_ctx[m][n2][j] *= alpha;
        int prow = m*16 + g*4 + j;
        lP[w][prow][0*16 + r16] = f2bf(p0);
        lP[w][prow][1*16 + r16] = f2bf(p1);
        lP[w][prow][2*16 + r16] = f2bf(p2);
        lP[w][prow][3*16 + r16] = f2bf(p3);
      }
    }

    // ctx += P @ V
    __builtin_amdgcn_s_setprio(1);
    #pragma unroll
    for (int ks2=0;ks2<2;ks2++){
      short8 af_p[2], bf_v[4];
      #pragma unroll
      for (int m=0;m<2;m++)
        af_p[m] = *(const short8*)&lP[w][m*16 + r16][ks2*32 + g*8];
      #pragma unroll
      for (int n=0;n<4;n++)
        bf_v[n] = *(const short8*)&lVt[cb][n*16 + r16][ks2*32 + g*8];
      #pragma unroll
      for (int m=0;m<2;m++)
        #pragma unroll
        for (int n=0;n<4;n++)
          acc_ctx[m][n] = __builtin_amdgcn_mfma_f32_16x16x32_bf16(af_p[m], bf_v[n], acc_ctx[m][n], 0, 0, 0);
    }
    __builtin_amdgcn_s_setprio(0);

    if (more){
      *(short8*)&lK[cb^1][key0][c8s] = kna;
      *(short8*)&lVt[cb^1][key0][c8s] = vna;
    }
    __syncthreads();
    cb ^= 1;
  }

  #pragma unroll
  for (int m=0;m<2;m++){
    #pragma unroll
    for (int j=0;j<4;j++){
      float inv = 1.0f / lrun[m][j];
      int gr = qbase + m*16 + g*4 + j;
      #pragma unroll
      for (int n=0;n<4;n++){
        ctxb[(size_t)(b*Ln + gr)*Dn + h*DHn + n*16 + r16] = f2bf(acc_ctx[m][n][j] * inv);
      }
    }
  }
}

// ---------------- layernorm: one wave per row (D=512), bf16 in -> bf16 out ----------------
__global__ __launch_bounds__(256) void ln_kernel(
    const ushort* __restrict__ hb, const float* __restrict__ gamma, const float* __restrict__ beta,
    ushort* __restrict__ out)
{
  int row = blockIdx.x*4 + (threadIdx.x >> 6);
  int lane = threadIdx.x & 63;
  const ushort* p = hb + (size_t)row*Dn + lane*8;
  short8 hv = *(const short8*)p;
  float v[8];
  #pragma unroll
  for (int j=0;j<8;j++) v[j] = bf2f((ushort)hv[j]);
  float s = 0.f, ss = 0.f;
  #pragma unroll
  for (int j=0;j<8;j++){ s += v[j]; ss += v[j]*v[j]; }
  #pragma unroll
  for (int off=32; off>0; off>>=1){ s += __shfl_xor(s, off); ss += __shfl_xor(ss, off); }
  float mu = s * (1.0f/Dn);
  float var = ss * (1.0f/Dn) - mu*mu;
  float rstd = rsqrtf(var + 1e-5f);
  ushort o8[8];
  #pragma unroll
  for (int j=0;j<8;j++) o8[j] = f2bf((v[j]-mu)*rstd*gamma[lane*8+j] + beta[lane*8+j]);
  ushort* op = out + (size_t)row*Dn + lane*8;
  *(ushort4*)op       = make_ushort4(o8[0],o8[1],o8[2],o8[3]);
  *(ushort4*)(op + 4) = make_ushort4(o8[4],o8[5],o8[6],o8[7]);
}

extern "C" void kernel_launch(void* const* d_in, const int* in_sizes, int n_in,
                              void* d_out, int out_size, void* d_ws, size_t ws_size,
                              hipStream_t stream) {
  (void)in_sizes; (void)n_in; (void)out_size; (void)ws_size;
  const float* x    = (const float*)d_in[0];
  const int*   mask = (const int*)d_in[1];
  const float* spk  = (const float*)d_in[2];
  const float* Wg   = (const float*)d_in[3];
  const float* Wq   = (const float*)d_in[4];  const float* bq = (const float*)d_in[5];
  const float* Wk   = (const float*)d_in[6];  const float* bk = (const float*)d_in[7];
  const float* Wv   = (const float*)d_in[8];  const float* bv = (const float*)d_in[9];
  const float* Wo   = (const float*)d_in[10]; const float* bo = (const float*)d_in[11];
  const float* lng  = (const float*)d_in[12]; const float* lnbeta = (const float*)d_in[13];
  const float* W1   = (const float*)d_in[14]; const float* b1 = (const float*)d_in[15];
  const float* W2   = (const float*)d_in[16]; const float* b2 = (const float*)d_in[17];
  float* out = (float*)d_out;

  char* w = (char*)d_ws;
  size_t o = 0;
  ushort* xbf   = (ushort*)(w + o); o += (size_t)Mn*Dn*2;    // dead after gate   } overlapped
  ushort* xinb  = (ushort*)(w + o); o += (size_t)Mn*Dn*2;    // dead after Wo     } by midb
  ushort* qkvb  = (ushort*)(w + o); o += (size_t)Mn*QKVS*2;  // dead after attn   }
  ushort* vtb   = (ushort*)(w + o); o += (size_t)Mn*Dn*2;    // V transposed [(b,h,dh)][key]
  ushort* ctxb  = (ushort*)(w + o); o += (size_t)Mn*Dn*2;
  ushort* hb16  = (ushort*)(w + o); o += (size_t)Mn*Dn*2;    // h residual, bf16
  ushort* lnbuf = (ushort*)(w + o); o += (size_t)Mn*Dn*2;
  ushort* wgb   = (ushort*)(w + o); o += (size_t)Dn*Dn*2;
  ushort* wqkvb = (ushort*)(w + o); o += (size_t)QKVS*Dn*2;
  ushort* wob   = (ushort*)(w + o); o += (size_t)Dn*Dn*2;
  ushort* w1b   = (ushort*)(w + o); o += (size_t)FFn*Dn*2;
  ushort* w2b   = (ushort*)(w + o); o += (size_t)Dn*FFn*2;
  float*  pebuf = (float*)(w + o);  o += (size_t)Ln*Dn*4;
  float*  bqkv  = (float*)(w + o);  o += (size_t)QKVS*4;
  ushort* midb  = xbf;  // M x FF bf16 (64MB), overlaps xbf+xinb+qkvb (all dead by ff1)

  // fused prep: x cvt + all weight cvts + PE + bias pack (one launch)
  hipLaunchKernelGGL(prep_kernel, dim3(11778), dim3(256), 0, stream,
                     x, xbf, Wg, Wq, Wk, Wv, Wo, W1, W2, bq, bk, bv,
                     wgb, wqkvb, wob, w1b, w2b, pebuf, bqkv);

  // gate: xin = sigmoid(x@Wg^T)*x + spk + pe  -> xinb (bf16; residual read = xbf)
  hipLaunchKernelGGL((gemm_kernel<0>), dim3((Dn/128)*(Mn/256)), dim3(512), 0, stream,
                     xbf, wgb, (const float*)nullptr, xbf, spk, pebuf,
                     (float*)nullptr, xinb, Dn, Dn, Dn/128);
  // fused qkv (128x256 tile, 768 balanced blocks): q,k -> qkvb[M][1536]; v -> vtb transposed
  hipLaunchKernelGGL(gemm128_kernel, dim3((QKVS/256)*(Mn/128)), dim3(512), 0, stream,
                     xinb, wqkvb, bqkv, qkvb, vtb, Dn, QKVS, QKVS/256);
  // attention (MFMA flash, 8-wave blocks)
  hipLaunchKernelGGL(attn_mfma_kernel, dim3(Ln/256, Hn, Bn), dim3(512), 0, stream,
                     qkvb, qkvb + 512, vtb, mask, ctxb);
  // h = ctx@Wo^T + bo + xin  -> hb16 (bf16)
  hipLaunchKernelGGL((gemm_kernel<2>), dim3((Dn/128)*(Mn/256)), dim3(512), 0, stream,
                     ctxb, wob, bo, xinb, (const float*)nullptr, (const float*)nullptr,
                     (float*)nullptr, hb16, Dn, Dn, Dn/128);
  // layernorm (bf16 in)
  hipLaunchKernelGGL(ln_kernel, dim3(Mn/4), dim3(256), 0, stream, hb16, lng, lnbeta, lnbuf);
  // mid = gelu(ln@W1^T + b1)  (256² tile, 512 balanced blocks)
  hipLaunchKernelGGL(gemm256_kernel, dim3((FFn/256)*(Mn/256)), dim3(512), 0, stream,
                     lnbuf, w1b, b1, midb, Dn, FFn, FFn/256);
  // out = gelu(mid@W2^T + b2) + h(bf16)
  hipLaunchKernelGGL((gemm_kernel<4>), dim3((Dn/128)*(Mn/256)), dim3(512), 0, stream,
                     midb, w2b, b2, hb16, (const float*)nullptr, (const float*)nullptr,
                     out, (ushort*)nullptr, FFn, Dn, Dn/128);
}

// Round 15
// 295.369 us; speedup vs baseline: 1.0281x; 1.0028x over previous
//
#include <hip/hip_runtime.h>
#include <math.h>

#define Bn 32
#define Ln 512
#define Dn 512
#define Hn 8
#define DHn 64
#define FFn 2048
#define Mn (Bn*Ln)   // 16384
#define QKVS 1536

typedef __attribute__((ext_vector_type(4))) float f32x4;
typedef __attribute__((ext_vector_type(8))) short short8;

__device__ __forceinline__ float bf2f(ushort u){ return __uint_as_float(((unsigned)u) << 16); }
__device__ __forceinline__ ushort f2bf(float f){
  unsigned u = __float_as_uint(f);
  u += 0x7FFFu + ((u >> 16) & 1u);
  return (ushort)(u >> 16);
}
// exact sigmoid-form of tanh-gelu: 0.5x(1+tanh(y)) == x*sigmoid(2y)
__device__ __forceinline__ float gelu_fast(float x){
  float y2 = 1.5957691216057308f * (x + 0.044715f*x*x*x);
  return x / (1.0f + __expf(-y2));
}

// async global->LDS, 16B per lane; LDS dest is wave-uniform base + lane*16
__device__ __forceinline__ void gload_lds16(const ushort* g, ushort* l){
  __builtin_amdgcn_global_load_lds(
      (__attribute__((address_space(1))) void*)(void*)g,
      (__attribute__((address_space(3))) void*)(void*)l, 16, 0, 0);
}

__device__ __forceinline__ void cvt4(const float* __restrict__ in, ushort* __restrict__ out, int u){
  float4 v = *(const float4*)(in + u*4);
  ushort4 o;
  o.x = f2bf(v.x); o.y = f2bf(v.y); o.z = f2bf(v.z); o.w = f2bf(v.w);
  *(ushort4*)(out + u*4) = o;
}

// ---------------- fused prep: x cvt + 7 weight cvts + PE table + qkv bias pack ----------------
__global__ __launch_bounds__(256) void prep_kernel(
    const float* __restrict__ x, ushort* __restrict__ xbf,
    const float* __restrict__ Wg, const float* __restrict__ Wq, const float* __restrict__ Wk,
    const float* __restrict__ Wv, const float* __restrict__ Wo, const float* __restrict__ W1,
    const float* __restrict__ W2,
    const float* __restrict__ bq, const float* __restrict__ bk, const float* __restrict__ bv,
    ushort* __restrict__ wgb, ushort* __restrict__ wqkvb, ushort* __restrict__ wob,
    ushort* __restrict__ w1b, ushort* __restrict__ w2b,
    float* __restrict__ pe, float* __restrict__ bqkv)
{
  int u = blockIdx.x*256 + threadIdx.x;
  const int XU = 2097152, WU = 65536, FU = 262144;
  if (u < XU){ cvt4(x, xbf, u); return; }             u -= XU;
  if (u < WU){ cvt4(Wg, wgb, u); return; }            u -= WU;
  if (u < WU){ cvt4(Wq, wqkvb, u); return; }          u -= WU;
  if (u < WU){ cvt4(Wk, wqkvb + 262144, u); return; } u -= WU;
  if (u < WU){ cvt4(Wv, wqkvb + 524288, u); return; } u -= WU;
  if (u < WU){ cvt4(Wo, wob, u); return; }            u -= WU;
  if (u < FU){ cvt4(W1, w1b, u); return; }            u -= FU;
  if (u < FU){ cvt4(W2, w2b, u); return; }            u -= FU;
  if (u < WU){                                        // PE table
    int e = u*4; int l = e >> 9; int d0 = e & 511;
    #pragma unroll
    for (int p=0;p<2;p++){
      int i = (d0 >> 1) + p;
      float dv = expf((float)(2*i) * (-9.210340371976184f/512.0f));
      float ang = (float)l * dv;
      pe[e + 2*p]     = sinf(ang);
      pe[e + 2*p + 1] = cosf(ang);
    }
    return;
  }
  u -= WU;
  if (u < 384){
    int e = u*4;
    #pragma unroll
    for (int j=0;j<4;j++){
      int i = e + j;
      bqkv[i] = (i < 512) ? bq[i] : (i < 1024) ? bk[i-512] : bv[i-1024];
    }
  }
}

// ---------------- GEMM A (R9): BM=256, BN=128, BK=64, 3-ring, 1 barrier/K-tile ----------------
// MODE: 0 gate (sigmoid(c)*bf16res + spk + pe -> bf16)
//       2 c + bias + bf16res -> bf16 (h)
//       4 gelu + bf16res -> f32 (final out)
template<int MODE>
__global__ __launch_bounds__(512) void gemm_kernel(
    const ushort* __restrict__ A, const ushort* __restrict__ W,
    const float* __restrict__ bias,
    const ushort* __restrict__ rbf,
    const float* __restrict__ spk, const float* __restrict__ pe,
    float* __restrict__ outf, ushort* __restrict__ outb,
    int K, int N, int gx)
{
  __shared__ ushort lbuf[3][24576];   // per buf: A 256x64 (16384) | B 128x64 (8192)
  int t = threadIdx.x;
  int wave = t >> 6, lane = t & 63;
  int wrow = wave >> 2, wcol = wave & 3;
  int g = lane >> 4, r16 = lane & 15;

  int nwg = gx * (Mn/256);
  int wg = blockIdx.x;
  int tile = (wg & 7)*(nwg >> 3) + (wg >> 3);
  int trow = tile / gx;
  int tcol = tile - trow*gx;
  int rowBase = trow * 256;
  int colBase = tcol * 128;

  int srow8 = lane >> 3;
  int sucol = ((lane & 7) ^ srow8) * 8;
  const ushort* gA = A + (size_t)(rowBase + wave*8 + srow8)*K + sucol;
  const ushort* gW = W + (size_t)(colBase + wave*8 + srow8)*K + sucol;

  int NT = K >> 6;

  f32x4 acc[8][2];
  #pragma unroll
  for (int m=0;m<8;m++)
    #pragma unroll
    for (int n=0;n<2;n++) acc[m][n] = (f32x4)0.0f;

  #pragma unroll
  for (int c=0;c<4;c++) gload_lds16(gA + (size_t)c*64*K,      &lbuf[0][c*4096 + wave*512]);
  #pragma unroll
  for (int c=0;c<2;c++) gload_lds16(gW + (size_t)c*64*K,      &lbuf[0][16384 + c*4096 + wave*512]);
  #pragma unroll
  for (int c=0;c<4;c++) gload_lds16(gA + (size_t)c*64*K + 64, &lbuf[1][c*4096 + wave*512]);
  #pragma unroll
  for (int c=0;c<2;c++) gload_lds16(gW + (size_t)c*64*K + 64, &lbuf[1][16384 + c*4096 + wave*512]);
  asm volatile("s_waitcnt vmcnt(6)" ::: "memory");
  __builtin_amdgcn_s_barrier();

  int cur = 0, stg = 2;
  for (int kt = 0; kt < NT; ++kt){
    if (kt + 2 < NT){
      int k0 = (kt + 2) << 6;
      #pragma unroll
      for (int c=0;c<4;c++) gload_lds16(gA + (size_t)c*64*K + k0, &lbuf[stg][c*4096 + wave*512]);
      #pragma unroll
      for (int c=0;c<2;c++) gload_lds16(gW + (size_t)c*64*K + k0, &lbuf[stg][16384 + c*4096 + wave*512]);
    }
    const ushort* ab = &lbuf[cur][0];
    const ushort* bb = &lbuf[cur][16384];
    __builtin_amdgcn_s_setprio(1);
    #pragma unroll
    for (int ks=0; ks<2; ks++){
      short8 af[8], bfr[2];
      #pragma unroll
      for (int m=0;m<8;m++){
        int row = wrow*128 + m*16 + r16;
        af[m] = *(const short8*)&ab[row*64 + (((ks<<2)+g) ^ (row & 7))*8];
      }
      #pragma unroll
      for (int n=0;n<2;n++){
        int row = wcol*32 + n*16 + r16;
        bfr[n] = *(const short8*)&bb[row*64 + (((ks<<2)+g) ^ (row & 7))*8];
      }
      #pragma unroll
      for (int m=0;m<8;m++)
        #pragma unroll
        for (int n=0;n<2;n++)
          acc[m][n] = __builtin_amdgcn_mfma_f32_16x16x32_bf16(af[m], bfr[n], acc[m][n], 0, 0, 0);
    }
    __builtin_amdgcn_s_setprio(0);
    if (kt + 1 < NT){
      if (kt + 2 < NT) asm volatile("s_waitcnt vmcnt(6)" ::: "memory");
      else             asm volatile("s_waitcnt vmcnt(0)" ::: "memory");
      __builtin_amdgcn_s_barrier();
    }
    cur = (cur == 2) ? 0 : cur + 1;
    stg = (stg == 2) ? 0 : stg + 1;
  }

  // ---- epilogue ----
  if constexpr (MODE == 0 || MODE == 2){
    __syncthreads();
    ushort* ct = &lbuf[0][0];   // 256x128 bf16 = 64KB
    #pragma unroll
    for (int m=0;m<8;m++){
      #pragma unroll
      for (int n=0;n<2;n++){
        int col = wcol*32 + n*16 + r16;
        int gc = colBase + col;
        #pragma unroll
        for (int j=0;j<4;j++){
          int row = wrow*128 + m*16 + g*4 + j;
          int gr = rowBase + row;
          size_t o = (size_t)gr * N + gc;
          float c = acc[m][n][j];
          ushort val;
          if constexpr (MODE == 0){
            float s = 1.0f/(1.0f + __expf(-c));
            val = f2bf(s * bf2f(rbf[o]) + spk[o] + pe[(gr & (Ln-1))*Dn + gc]);
          } else {
            val = f2bf(c + bias[gc] + bf2f(rbf[o]));
          }
          ct[row*128 + (col ^ ((row & 7) << 3))] = val;
        }
      }
    }
    __syncthreads();
    int r = t >> 1, ch = (t & 1)*64;
    ushort* dst = outb + (size_t)(rowBase + r)*N + colBase + ch;
    #pragma unroll
    for (int q=0;q<8;q++){
      int col = (ch + q*8) ^ ((r & 7) << 3);
      *(short8*)(dst + q*8) = *(const short8*)&ct[r*128 + col];
    }
  } else {
    #pragma unroll
    for (int m=0;m<8;m++){
      #pragma unroll
      for (int n=0;n<2;n++){
        int gc = colBase + wcol*32 + n*16 + r16;
        #pragma unroll
        for (int j=0;j<4;j++){
          int gr = rowBase + wrow*128 + m*16 + g*4 + j;
          size_t o = (size_t)gr * N + gc;
          outf[o] = gelu_fast(acc[m][n][j] + bias[gc]) + bf2f(rbf[o]);
        }
      }
    }
  }
}

// ---------------- GEMM B (R8): BM=BN=256, BK=64, dbuf, vmcnt(8) 2-barrier ----------------
// Used for ff1 (512 blocks = 2.0 balanced waves). gelu->bf16
__global__ __launch_bounds__(512) void gemm256_kernel(
    const ushort* __restrict__ A, const ushort* __restrict__ W,
    const float* __restrict__ bias,
    ushort* __restrict__ outb,
    int K, int N, int gx)
{
  __shared__ ushort lbuf[2][2][16384];   // [dbuf][A/W][256 rows x 64 cols]
  int t = threadIdx.x;
  int wave = t >> 6, lane = t & 63;
  int wrow = wave >> 2, wcol = wave & 3;
  int g = lane >> 4, r16 = lane & 15;

  int nwg = gx * (Mn/256);
  int wg = blockIdx.x;
  int tile = (wg & 7)*(nwg >> 3) + (wg >> 3);
  int trow = tile / gx;
  int tcol = tile - trow*gx;
  int rowBase = trow * 256;
  int colBase = tcol * 256;

  int srow8 = lane >> 3;
  int sucol = ((lane & 7) ^ srow8) * 8;
  const ushort* gA = A + (size_t)(rowBase + wave*8 + srow8)*K + sucol;
  const ushort* gW = W + (size_t)(colBase + wave*8 + srow8)*K + sucol;

  f32x4 acc[8][4];
  #pragma unroll
  for (int m=0;m<8;m++)
    #pragma unroll
    for (int n=0;n<4;n++) acc[m][n] = (f32x4)0.0f;

  #pragma unroll
  for (int c=0;c<4;c++){
    gload_lds16(gA + (size_t)c*64*K, &lbuf[0][0][c*4096 + wave*512]);
    gload_lds16(gW + (size_t)c*64*K, &lbuf[0][1][c*4096 + wave*512]);
  }

  int cb = 0;
  for (int k0 = 0; k0 < K; k0 += 64){
    if (k0 + 64 < K){
      #pragma unroll
      for (int c=0;c<4;c++){
        gload_lds16(gA + (size_t)c*64*K + k0 + 64, &lbuf[cb^1][0][c*4096 + wave*512]);
        gload_lds16(gW + (size_t)c*64*K + k0 + 64, &lbuf[cb^1][1][c*4096 + wave*512]);
      }
      asm volatile("s_waitcnt vmcnt(8)" ::: "memory");
    } else {
      asm volatile("s_waitcnt vmcnt(0)" ::: "memory");
    }
    __builtin_amdgcn_s_barrier();
    #pragma unroll
    for (int ks=0; ks<2; ks++){
      short8 af[8], bfr[4];
      #pragma unroll
      for (int m=0;m<8;m++){
        int row = wrow*128 + m*16 + r16;
        af[m] = *(const short8*)&lbuf[cb][0][row*64 + (((ks<<2)+g) ^ (r16 & 7))*8];
      }
      #pragma unroll
      for (int n=0;n<4;n++){
        int row = wcol*64 + n*16 + r16;
        bfr[n] = *(const short8*)&lbuf[cb][1][row*64 + (((ks<<2)+g) ^ (r16 & 7))*8];
      }
      #pragma unroll
      for (int m=0;m<8;m++)
        #pragma unroll
        for (int n=0;n<4;n++)
          acc[m][n] = __builtin_amdgcn_mfma_f32_16x16x32_bf16(af[m], bfr[n], acc[m][n], 0, 0, 0);
    }
    __builtin_amdgcn_s_barrier();
    cb ^= 1;
  }

  ushort* ct = &lbuf[0][0][0];   // 256x256 bf16 = 128KB
  #pragma unroll
  for (int m=0;m<8;m++){
    #pragma unroll
    for (int n=0;n<4;n++){
      int col = wcol*64 + n*16 + r16;
      int gc = colBase + col;
      #pragma unroll
      for (int j=0;j<4;j++){
        int row = wrow*128 + m*16 + g*4 + j;
        ct[row*256 + (col ^ ((row & 7) << 3))] = f2bf(gelu_fast(acc[m][n][j] + bias[gc]));
      }
    }
  }
  __syncthreads();
  int r = t >> 1, ch = (t & 1)*128;
  ushort* dst = outb + (size_t)(rowBase + r)*N + colBase + ch;
  #pragma unroll
  for (int q=0;q<16;q++){
    int col = (ch + q*8) ^ ((r & 7) << 3);
    *(short8*)(dst + q*8) = *(const short8*)&ct[r*256 + col];
  }
}

// ---------------- GEMM C: BM=128, BN=256, BK=64, 3-ring — qkv only ----------------
// grid = 768 blocks = 3.0 balanced occupancy-waves.
__global__ __launch_bounds__(512) void gemm128_kernel(
    const ushort* __restrict__ A, const ushort* __restrict__ W,
    const float* __restrict__ bias,
    ushort* __restrict__ outb, ushort* __restrict__ outb2,
    int K, int N, int gx)
{
  __shared__ ushort lbuf[3][24576];   // per buf: A 128x64 (8192) | B 256x64 (16384)
  int t = threadIdx.x;
  int wave = t >> 6, lane = t & 63;
  int wrow = wave >> 2, wcol = wave & 3;   // 2x4, wave tile 64x64
  int g = lane >> 4, r16 = lane & 15;

  int nwg = gx * (Mn/128);   // 768, %8==0
  int wg = blockIdx.x;
  int tile = (wg & 7)*(nwg >> 3) + (wg >> 3);
  int trow = tile / gx;
  int tcol = tile - trow*gx;
  int rowBase = trow * 128;
  int colBase = tcol * 256;

  int srow8 = lane >> 3;
  int sucol = ((lane & 7) ^ srow8) * 8;
  const ushort* gA = A + (size_t)(rowBase + wave*8 + srow8)*K + sucol;
  const ushort* gW = W + (size_t)(colBase + wave*8 + srow8)*K + sucol;

  int NT = K >> 6;

  f32x4 acc[4][4];
  #pragma unroll
  for (int m=0;m<4;m++)
    #pragma unroll
    for (int n=0;n<4;n++) acc[m][n] = (f32x4)0.0f;

  #pragma unroll
  for (int c=0;c<2;c++) gload_lds16(gA + (size_t)c*64*K,      &lbuf[0][c*4096 + wave*512]);
  #pragma unroll
  for (int c=0;c<4;c++) gload_lds16(gW + (size_t)c*64*K,      &lbuf[0][8192 + c*4096 + wave*512]);
  #pragma unroll
  for (int c=0;c<2;c++) gload_lds16(gA + (size_t)c*64*K + 64, &lbuf[1][c*4096 + wave*512]);
  #pragma unroll
  for (int c=0;c<4;c++) gload_lds16(gW + (size_t)c*64*K + 64, &lbuf[1][8192 + c*4096 + wave*512]);
  asm volatile("s_waitcnt vmcnt(6)" ::: "memory");
  __builtin_amdgcn_s_barrier();

  int cur = 0, stg = 2;
  for (int kt = 0; kt < NT; ++kt){
    if (kt + 2 < NT){
      int k0 = (kt + 2) << 6;
      #pragma unroll
      for (int c=0;c<2;c++) gload_lds16(gA + (size_t)c*64*K + k0, &lbuf[stg][c*4096 + wave*512]);
      #pragma unroll
      for (int c=0;c<4;c++) gload_lds16(gW + (size_t)c*64*K + k0, &lbuf[stg][8192 + c*4096 + wave*512]);
    }
    const ushort* ab = &lbuf[cur][0];
    const ushort* bb = &lbuf[cur][8192];
    __builtin_amdgcn_s_setprio(1);
    #pragma unroll
    for (int ks=0; ks<2; ks++){
      short8 af[4], bfr[4];
      #pragma unroll
      for (int m=0;m<4;m++){
        int row = wrow*64 + m*16 + r16;
        af[m] = *(const short8*)&ab[row*64 + (((ks<<2)+g) ^ (row & 7))*8];
      }
      #pragma unroll
      for (int n=0;n<4;n++){
        int row = wcol*64 + n*16 + r16;
        bfr[n] = *(const short8*)&bb[row*64 + (((ks<<2)+g) ^ (row & 7))*8];
      }
      #pragma unroll
      for (int m=0;m<4;m++)
        #pragma unroll
        for (int n=0;n<4;n++)
          acc[m][n] = __builtin_amdgcn_mfma_f32_16x16x32_bf16(af[m], bfr[n], acc[m][n], 0, 0, 0);
    }
    __builtin_amdgcn_s_setprio(0);
    if (kt + 1 < NT){
      if (kt + 2 < NT) asm volatile("s_waitcnt vmcnt(6)" ::: "memory");
      else             asm volatile("s_waitcnt vmcnt(0)" ::: "memory");
      __builtin_amdgcn_s_barrier();
    }
    cur = (cur == 2) ? 0 : cur + 1;
    stg = (stg == 2) ? 0 : stg + 1;
  }

  // ---- epilogue ----
  bool vpart = (colBase >= 1024);
  if (!vpart){
    __syncthreads();
    ushort* ct = &lbuf[0][0];   // 128x256 bf16 = 64KB
    #pragma unroll
    for (int m=0;m<4;m++){
      #pragma unroll
      for (int n=0;n<4;n++){
        int col = wcol*64 + n*16 + r16;
        int gc = colBase + col;
        float sc = (gc < 512) ? 0.125f : 1.0f;
        #pragma unroll
        for (int j=0;j<4;j++){
          int row = wrow*64 + m*16 + g*4 + j;
          ct[row*256 + (col ^ ((row & 7) << 3))] = f2bf((acc[m][n][j] + bias[gc]) * sc);
        }
      }
    }
    __syncthreads();
    int r = t >> 2, ch = (t & 3)*64;
    ushort* dst = outb + (size_t)(rowBase + r)*N + colBase + ch;
    #pragma unroll
    for (int q=0;q<8;q++){
      int col = (ch + q*8) ^ ((r & 7) << 3);
      *(short8*)(dst + q*8) = *(const short8*)&ct[r*256 + col];
    }
  } else {
    #pragma unroll
    for (int m=0;m<4;m++){
      #pragma unroll
      for (int n=0;n<4;n++){
        int gc = colBase + wcol*64 + n*16 + r16;
        int dhg = gc - 1024;
        int gr0 = rowBase + wrow*64 + m*16 + g*4;
        int bb2 = gr0 >> 9, l0 = gr0 & 511;
        ushort4 o4;
        o4.x = f2bf(acc[m][n][0] + bias[gc]);
        o4.y = f2bf(acc[m][n][1] + bias[gc]);
        o4.z = f2bf(acc[m][n][2] + bias[gc]);
        o4.w = f2bf(acc[m][n][3] + bias[gc]);
        *(ushort4*)(outb2 + ((size_t)(bb2*Hn + (dhg>>6))*DHn + (dhg & 63))*Ln + l0) = o4;
      }
    }
  }
}

// ---------------- MFMA flash attention: 8 waves x 32 q-rows (256 rows/block) ----------------
__global__ __launch_bounds__(512) void attn_mfma_kernel(
    const ushort* __restrict__ qb, const ushort* __restrict__ kb, const ushort* __restrict__ vtb,
    const int* __restrict__ mask, ushort* __restrict__ ctxb)
{
  __shared__ ushort lK[2][64][72];
  __shared__ ushort lVt[2][64][72];
  __shared__ ushort lP[8][32][72];

  int t = threadIdx.x;
  int w = t >> 6, lane = t & 63;
  int g = lane >> 4, r16 = lane & 15;
  int b = blockIdx.z, h = blockIdx.y;
  int qbase = blockIdx.x*256 + w*32;

  int key0 = t >> 3;
  int c8s = (t & 7) * 8;
  const ushort* kbase = kb + (size_t)(b*Ln)*QKVS + h*DHn + c8s;
  const ushort* vt = vtb + (size_t)((b*Hn + h)*DHn) * Ln;   // [dh][key]

  short8 af_q[2][2];
  #pragma unroll
  for (int m=0;m<2;m++)
    #pragma unroll
    for (int ks=0;ks<2;ks++)
      af_q[m][ks] = *(const short8*)(qb + (size_t)(b*Ln + qbase + m*16 + r16)*QKVS + h*DHn + ks*32 + g*8);

  f32x4 acc_ctx[2][4];
  #pragma unroll
  for (int m=0;m<2;m++)
    #pragma unroll
    for (int n=0;n<4;n++) acc_ctx[m][n] = (f32x4)0.0f;
  float mrun[2][4], lrun[2][4];
  #pragma unroll
  for (int m=0;m<2;m++)
    #pragma unroll
    for (int j=0;j<4;j++){ mrun[m][j] = -INFINITY; lrun[m][j] = 0.0f; }

  {
    short8 ka = *(const short8*)(kbase + (size_t)key0*QKVS);
    short8 va = *(const short8*)(vt + (size_t)key0*Ln + c8s);
    *(short8*)&lK[0][key0][c8s] = ka;
    *(short8*)&lVt[0][key0][c8s] = va;
  }
  __syncthreads();
  int cb = 0;

  for (int kb0 = 0; kb0 < Ln; kb0 += 64){
    short8 kna, vna;
    bool more = (kb0 + 64 < Ln);
    if (more){
      kna = *(const short8*)(kbase + (size_t)(kb0 + 64 + key0)*QKVS);
      vna = *(const short8*)(vt + (size_t)key0*Ln + kb0 + 64 + c8s);
    }

    // S = Q @ K^T
    f32x4 acc_s[2][4];
    #pragma unroll
    for (int m=0;m<2;m++)
      #pragma unroll
      for (int n=0;n<4;n++) acc_s[m][n] = (f32x4)0.0f;
    __builtin_amdgcn_s_setprio(1);
    #pragma unroll
    for (int ks=0;ks<2;ks++){
      short8 bf_k[4];
      #pragma unroll
      for (int n=0;n<4;n++)
        bf_k[n] = *(const short8*)&lK[cb][n*16 + r16][ks*32 + g*8];
      #pragma unroll
      for (int m=0;m<2;m++)
        #pragma unroll
        for (int n=0;n<4;n++)
          acc_s[m][n] = __builtin_amdgcn_mfma_f32_16x16x32_bf16(af_q[m][ks], bf_k[n], acc_s[m][n], 0, 0, 0);
    }
    __builtin_amdgcn_s_setprio(0);

    // mask keys
    #pragma unroll
    for (int n=0;n<4;n++){
      if (mask[b*Ln + kb0 + n*16 + r16] == 0){
        #pragma unroll
        for (int m=0;m<2;m++)
          #pragma unroll
          for (int j=0;j<4;j++) acc_s[m][n][j] = -1e10f;
      }
    }

    // online softmax; P -> bf16 in wave-private LDS
    #pragma unroll
    for (int m=0;m<2;m++){
      #pragma unroll
      for (int j=0;j<4;j++){
        float tmax = fmaxf(fmaxf(acc_s[m][0][j], acc_s[m][1][j]),
                           fmaxf(acc_s[m][2][j], acc_s[m][3][j]));
        #pragma unroll
        for (int off=1; off<16; off<<=1) tmax = fmaxf(tmax, __shfl_xor(tmax, off));
        float newm = fmaxf(mrun[m][j], tmax);
        float alpha = __expf(mrun[m][j] - newm);
        float p0 = __expf(acc_s[m][0][j] - newm);
        float p1 = __expf(acc_s[m][1][j] - newm);
        float p2 = __expf(acc_s[m][2][j] - newm);
        float p3 = __expf(acc_s[m][3][j] - newm);
        float tsum = (p0+p1)+(p2+p3);
        #pragma unroll
        for (int off=1; off<16; off<<=1) tsum += __shfl_xor(tsum, off);
        lrun[m][j] = lrun[m][j]*alpha + tsum;
        mrun[m][j] = newm;
        #pragma unroll
        for (int n2=0;n2<4;n2++) acc_ctx[m][n2][j] *= alpha;
        int prow = m*16 + g*4 + j;
        lP[w][prow][0*16 + r16] = f2bf(p0);
        lP[w][prow][1*16 + r16] = f2bf(p1);
        lP[w][prow][2*16 + r16] = f2bf(p2);
        lP[w][prow][3*16 + r16] = f2bf(p3);
      }
    }

    // ctx += P @ V
    __builtin_amdgcn_s_setprio(1);
    #pragma unroll
    for (int ks2=0;ks2<2;ks2++){
      short8 af_p[2], bf_v[4];
      #pragma unroll
      for (int m=0;m<2;m++)
        af_p[m] = *(const short8*)&lP[w][m*16 + r16][ks2*32 + g*8];
      #pragma unroll
      for (int n=0;n<4;n++)
        bf_v[n] = *(const short8*)&lVt[cb][n*16 + r16][ks2*32 + g*8];
      #pragma unroll
      for (int m=0;m<2;m++)
        #pragma unroll
        for (int n=0;n<4;n++)
          acc_ctx[m][n] = __builtin_amdgcn_mfma_f32_16x16x32_bf16(af_p[m], bf_v[n], acc_ctx[m][n], 0, 0, 0);
    }
    __builtin_amdgcn_s_setprio(0);

    if (more){
      *(short8*)&lK[cb^1][key0][c8s] = kna;
      *(short8*)&lVt[cb^1][key0][c8s] = vna;
    }
    __syncthreads();
    cb ^= 1;
  }

  #pragma unroll
  for (int m=0;m<2;m++){
    #pragma unroll
    for (int j=0;j<4;j++){
      float inv = 1.0f / lrun[m][j];
      int gr = qbase + m*16 + g*4 + j;
      #pragma unroll
      for (int n=0;n<4;n++){
        ctxb[(size_t)(b*Ln + gr)*Dn + h*DHn + n*16 + r16] = f2bf(acc_ctx[m][n][j] * inv);
      }
    }
  }
}

// ---------------- layernorm: one wave per row (D=512), bf16 in -> bf16 out ----------------
__global__ __launch_bounds__(256) void ln_kernel(
    const ushort* __restrict__ hb, const float* __restrict__ gamma, const float* __restrict__ beta,
    ushort* __restrict__ out)
{
  int row = blockIdx.x*4 + (threadIdx.x >> 6);
  int lane = threadIdx.x & 63;
  const ushort* p = hb + (size_t)row*Dn + lane*8;
  short8 hv = *(const short8*)p;
  float v[8];
  #pragma unroll
  for (int j=0;j<8;j++) v[j] = bf2f((ushort)hv[j]);
  float s = 0.f, ss = 0.f;
  #pragma unroll
  for (int j=0;j<8;j++){ s += v[j]; ss += v[j]*v[j]; }
  #pragma unroll
  for (int off=32; off>0; off>>=1){ s += __shfl_xor(s, off); ss += __shfl_xor(ss, off); }
  float mu = s * (1.0f/Dn);
  float var = ss * (1.0f/Dn) - mu*mu;
  float rstd = rsqrtf(var + 1e-5f);
  ushort o8[8];
  #pragma unroll
  for (int j=0;j<8;j++) o8[j] = f2bf((v[j]-mu)*rstd*gamma[lane*8+j] + beta[lane*8+j]);
  ushort* op = out + (size_t)row*Dn + lane*8;
  *(ushort4*)op       = make_ushort4(o8[0],o8[1],o8[2],o8[3]);
  *(ushort4*)(op + 4) = make_ushort4(o8[4],o8[5],o8[6],o8[7]);
}

extern "C" void kernel_launch(void* const* d_in, const int* in_sizes, int n_in,
                              void* d_out, int out_size, void* d_ws, size_t ws_size,
                              hipStream_t stream) {
  (void)in_sizes; (void)n_in; (void)out_size; (void)ws_size;
  const float* x    = (const float*)d_in[0];
  const int*   mask = (const int*)d_in[1];
  const float* spk  = (const float*)d_in[2];
  const float* Wg   = (const float*)d_in[3];
  const float* Wq   = (const float*)d_in[4];  const float* bq = (const float*)d_in[5];
  const float* Wk   = (const float*)d_in[6];  const float* bk = (const float*)d_in[7];
  const float* Wv   = (const float*)d_in[8];  const float* bv = (const float*)d_in[9];
  const float* Wo   = (const float*)d_in[10]; const float* bo = (const float*)d_in[11];
  const float* lng  = (const float*)d_in[12]; const float* lnbeta = (const float*)d_in[13];
  const float* W1   = (const float*)d_in[14]; const float* b1 = (const float*)d_in[15];
  const float* W2   = (const float*)d_in[16]; const float* b2 = (const float*)d_in[17];
  float* out = (float*)d_out;

  char* w = (char*)d_ws;
  size_t o = 0;
  ushort* xbf   = (ushort*)(w + o); o += (size_t)Mn*Dn*2;    // dead after gate   } overlapped
  ushort* xinb  = (ushort*)(w + o); o += (size_t)Mn*Dn*2;    // dead after Wo     } by midb
  ushort* qkvb  = (ushort*)(w + o); o += (size_t)Mn*QKVS*2;  // dead after attn   }
  ushort* vtb   = (ushort*)(w + o); o += (size_t)Mn*Dn*2;    // V transposed [(b,h,dh)][key]
  ushort* ctxb  = (ushort*)(w + o); o += (size_t)Mn*Dn*2;
  ushort* hb16  = (ushort*)(w + o); o += (size_t)Mn*Dn*2;    // h residual, bf16
  ushort* lnbuf = (ushort*)(w + o); o += (size_t)Mn*Dn*2;
  ushort* wgb   = (ushort*)(w + o); o += (size_t)Dn*Dn*2;
  ushort* wqkvb = (ushort*)(w + o); o += (size_t)QKVS*Dn*2;
  ushort* wob   = (ushort*)(w + o); o += (size_t)Dn*Dn*2;
  ushort* w1b   = (ushort*)(w + o); o += (size_t)FFn*Dn*2;
  ushort* w2b   = (ushort*)(w + o); o += (size_t)Dn*FFn*2;
  float*  pebuf = (float*)(w + o);  o += (size_t)Ln*Dn*4;
  float*  bqkv  = (float*)(w + o);  o += (size_t)QKVS*4;
  ushort* midb  = xbf;  // M x FF bf16 (64MB), overlaps xbf+xinb+qkvb (all dead by ff1)

  // fused prep: x cvt + all weight cvts + PE + bias pack (one launch)
  hipLaunchKernelGGL(prep_kernel, dim3(11778), dim3(256), 0, stream,
                     x, xbf, Wg, Wq, Wk, Wv, Wo, W1, W2, bq, bk, bv,
                     wgb, wqkvb, wob, w1b, w2b, pebuf, bqkv);

  // gate: xin = sigmoid(x@Wg^T)*x + spk + pe  -> xinb (bf16; residual read = xbf)
  hipLaunchKernelGGL((gemm_kernel<0>), dim3((Dn/128)*(Mn/256)), dim3(512), 0, stream,
                     xbf, wgb, (const float*)nullptr, xbf, spk, pebuf,
                     (float*)nullptr, xinb, Dn, Dn, Dn/128);
  // fused qkv (128x256 tile, 768 balanced blocks): q,k -> qkvb[M][1536]; v -> vtb transposed
  hipLaunchKernelGGL(gemm128_kernel, dim3((QKVS/256)*(Mn/128)), dim3(512), 0, stream,
                     xinb, wqkvb, bqkv, qkvb, vtb, Dn, QKVS, QKVS/256);
  // attention (MFMA flash, 8-wave blocks)
  hipLaunchKernelGGL(attn_mfma_kernel, dim3(Ln/256, Hn, Bn), dim3(512), 0, stream,
                     qkvb, qkvb + 512, vtb, mask, ctxb);
  // h = ctx@Wo^T + bo + xin  -> hb16 (bf16)
  hipLaunchKernelGGL((gemm_kernel<2>), dim3((Dn/128)*(Mn/256)), dim3(512), 0, stream,
                     ctxb, wob, bo, xinb, (const float*)nullptr, (const float*)nullptr,
                     (float*)nullptr, hb16, Dn, Dn, Dn/128);
  // layernorm (bf16 in)
  hipLaunchKernelGGL(ln_kernel, dim3(Mn/4), dim3(256), 0, stream, hb16, lng, lnbeta, lnbuf);
  // mid = gelu(ln@W1^T + b1)  (256² tile, 512 balanced blocks)
  hipLaunchKernelGGL(gemm256_kernel, dim3((FFn/256)*(Mn/256)), dim3(512), 0, stream,
                     lnbuf, w1b, b1, midb, Dn, FFn, FFn/256);
  // out = gelu(mid@W2^T + b2) + h(bf16)
  hipLaunchKernelGGL((gemm_kernel<4>), dim3((Dn/128)*(Mn/256)), dim3(512), 0, stream,
                     midb, w2b, b2, hb16, (const float*)nullptr, (const float*)nullptr,
                     out, (ushort*)nullptr, FFn, Dn, Dn/128);
}